// Round 6
// baseline (1132.417 us; speedup 1.0000x reference)
//
#include <hip/hip_runtime.h>
#include <hip/hip_bf16.h>
#include <stdint.h>

typedef unsigned short u16;
typedef unsigned int   u32;
typedef __attribute__((ext_vector_type(8))) short bf16x8;
typedef __attribute__((ext_vector_type(4))) float f32x4;

__device__ __forceinline__ float us2f(u16 u){ return __uint_as_float(((u32)u)<<16); }
__device__ __forceinline__ float lo2f(u32 w){ return __uint_as_float(w<<16); }
__device__ __forceinline__ float hi2f(u32 w){ return __uint_as_float(w & 0xffff0000u); }
__device__ __forceinline__ u16 f2us(float f){
  u32 u = __float_as_uint(f);
  u32 r = (u + 0x7FFFu + ((u>>16)&1u)) >> 16;   // RNE
  return (u16)r;
}
__device__ __forceinline__ u32 pk2(float a, float b){ return (u32)f2us(a) | ((u32)f2us(b)<<16); }

// ---------------- prep: x (b,r,w) f32 -> xT[b][w][r] bf16 ----------------
__global__ __launch_bounds__(256) void k_prep_x(const float* __restrict__ x, u16* __restrict__ xT){
  __shared__ float tile[64][65];
  const int b = blockIdx.x, t = threadIdx.x;
  #pragma unroll
  for (int q=0;q<4;q++){
    int idx = q*256 + t, r = idx>>4, w4 = (idx&15)*4;
    float4 v = *(const float4*)&x[((size_t)b*64 + r)*64 + w4];
    tile[r][w4]=v.x; tile[r][w4+1]=v.y; tile[r][w4+2]=v.z; tile[r][w4+3]=v.w;
  }
  __syncthreads();
  #pragma unroll
  for (int q=0;q<2;q++){
    int idx = q*256 + t, w = idx>>3, rc = idx&7;
    uint4 o;
    o.x = pk2(tile[rc*8+0][w], tile[rc*8+1][w]);
    o.y = pk2(tile[rc*8+2][w], tile[rc*8+3][w]);
    o.z = pk2(tile[rc*8+4][w], tile[rc*8+5][w]);
    o.w = pk2(tile[rc*8+6][w], tile[rc*8+7][w]);
    *(uint4*)&xT[((size_t)b*64 + w)*64 + rc*8] = o;
  }
}

// ---------------- prep: W (64h,31o,CI,64r,3dw) f32 -> Wp[h][i][dw][o32][r64] bf16 ----------------
__global__ __launch_bounds__(256) void k_prep_w(const float* __restrict__ W,
        u16* __restrict__ Wp, int CI){
  __shared__ float rowW[5952];   // [o 31][j 192]
  const int h = blockIdx.x, i = blockIdx.y, t = threadIdx.x;
  for (int idx=t; idx<1488; idx+=256){
    int o = idx/48, j4 = (idx - o*48)*4;
    float4 v = *(const float4*)&W[ (((size_t)h*31 + o)*CI + i)*192 + j4 ];
    *(float4*)&rowW[o*192 + j4] = v;
  }
  __syncthreads();
  for (int idx=t; idx<768; idx+=256){
    int dw = idx>>8, rem = idx&255, o = rem>>3, rc = rem&7;
    uint4 ov = {0,0,0,0};
    if (o < 31){
      const float* s = &rowW[o*192 + dw];
      ov.x = pk2(s[(rc*8+0)*3], s[(rc*8+1)*3]);
      ov.y = pk2(s[(rc*8+2)*3], s[(rc*8+3)*3]);
      ov.z = pk2(s[(rc*8+4)*3], s[(rc*8+5)*3]);
      ov.w = pk2(s[(rc*8+6)*3], s[(rc*8+7)*3]);
    }
    *(uint4*)&Wp[ ((((size_t)h*CI + i)*3 + dw)*32 + o)*64 + rc*8 ] = ov;
  }
}

// ---------------- bf16 transpose: in[b][o][h][w] -> out[b][o][w][h] ----------------
// XOR unit-swizzle makes the column gather bank-conflict-free.
__global__ __launch_bounds__(256) void k_tr(const u16* __restrict__ in, u16* __restrict__ outp){
  __shared__ u16 tile[64*72];
  const int b = blockIdx.x, o = blockIdx.y, t = threadIdx.x;
  const uint4* src = (const uint4*)(in + ((size_t)b*31 + o)*4096);
  #pragma unroll
  for (int q=0;q<2;q++){
    int idx = q*256 + t, hh = idx>>3, u = idx&7;
    *(uint4*)&tile[hh*72 + ((u ^ ((hh>>3)&7))*8)] = src[idx];
  }
  __syncthreads();
  u16* dst = outp + ((size_t)b*31 + o)*4096;
  #pragma unroll
  for (int q=0;q<2;q++){
    int idx = q*256 + t, w = idx>>3, hc = (idx&7)*8;
    u32 ow[4];
    #pragma unroll
    for (int j=0;j<4;j++){
      int h0 = hc + j*2, h1 = h0 + 1;
      u16 a = tile[h0*72 + (((w>>3) ^ ((h0>>3)&7))*8) + (w&7)];
      u16 bb= tile[h1*72 + (((w>>3) ^ ((h1>>3)&7))*8) + (w&7)];
      ow[j] = (u32)a | ((u32)bb<<16);
    }
    uint4 ov = {ow[0], ow[1], ow[2], ow[3]};
    *(uint4*)&dst[(size_t)w*64 + hc] = ov;
  }
}

// ---------------- spatial layer via MFMA, wave-independent ----------------
// inT_g: [b][i][w][r] bf16 ; Wp: [h][i][dw][o32][r64] bf16 ; bias (64,31) f32
// mode 0: outF[b][o][h][w] f32 ; mode 1: outT[b][o][h][w] bf16 (natural layout)
// Each WAVE independently owns (h, b, w-half): 4096 waves = 1024 blocks x 4 waves
// = 16 waves/CU (launch_bounds caps VGPR at 128). NO barriers anywhere: each wave
// stages its own 34-row channel slice into private LDS (4.9 KB, single-buffered;
// program order within a wave makes double-buffering unnecessary). All waits are
// wave-local compiler-inserted vmcnt/lgkmcnt, hidden by 4 waves/SIMD TLP.
// h tied to XCD (8 h per XCD -> 3 MB Wp slice L2-resident).
__global__ __launch_bounds__(256, 4) void k_spatial2(const u16* __restrict__ inT_g,
        const u16* __restrict__ Wp, const float* __restrict__ bias,
        float* __restrict__ outF, u16* __restrict__ outT, int CI, int mode){
  __shared__ __align__(16) u16 S[4][34*72];   // per-wave private [lw 0..33][r pad72]
  const int t    = threadIdx.x;
  const int wv   = t>>6;
  const int lane = t&63;
  const int l15  = lane&15;
  const int quad = lane>>4;
  // 1024 blocks = 8 xcd * 128: per block (h-pair, b); per wave (h, wh)
  const int wg  = blockIdx.x;
  const int xcd = wg & 7;
  const int li  = wg >> 3;            // 0..127
  const int hp  = li >> 5;            // 0..3
  const int b   = li & 31;
  const int h   = xcd*8 + hp*2 + (wv&1);
  const int wh  = wv >> 1;
  const int w0  = wh*32;

  u16* L = S[wv];

  f32x4 acc[2][2];
  #pragma unroll
  for (int n=0;n<2;n++)
    #pragma unroll
    for (int ms=0;ms<2;ms++) acc[n][ms] = (f32x4){0.f,0.f,0.f,0.f};

  const uint4* srcb = (const uint4*)(inT_g + (size_t)b*CI*4096);
  const u16*   wrow = Wp + (size_t)h*CI*3*32*64;

  // per-wave prefetch regs: 34 rows x 8 chunks = 272 uint4 over 64 lanes = 4 + tail
  uint4 pf[5];
  const uint4 zz = {0,0,0,0};

  auto issue_pf = [&](int ch){
    const uint4* src = srcb + (size_t)ch*512;
    #pragma unroll
    for (int k=0;k<4;k++){
      int c = lane + 64*k, row = c>>3, cn = c&7;
      int gw = w0 - 1 + row;
      pf[k] = zz;
      if (gw >= 0 && gw < 64) pf[k] = src[gw*8 + cn];
    }
    {
      int c = 256 + lane, row = c>>3, cn = c&7;
      int gw = w0 - 1 + row;
      pf[4] = zz;
      if (lane < 16 && gw >= 0 && gw < 64) pf[4] = src[gw*8 + cn];
    }
  };

  issue_pf(0);

  for (int i=0;i<CI;i++){
    // stage channel i from pf regs into private LDS (compiler waits vmcnt)
    #pragma unroll
    for (int k=0;k<4;k++){
      int c = lane + 64*k, row = c>>3, cn = c&7;
      *(uint4*)&L[row*72 + cn*8] = pf[k];
    }
    if (lane < 16){
      int c = 256 + lane, row = c>>3, cn = c&7;
      *(uint4*)&L[row*72 + cn*8] = pf[4];
    }
    // issue prefetch of channel i+1 (vm, in flight during compute)
    if (i+1 < CI) issue_pf(i+1);

    const u16* wbase = wrow + (size_t)i*6144;   // 3*32*64
    #pragma unroll
    for (int kh=0; kh<2; kh++){
      // weight fragments for this kh (L2-hot)
      bf16x8 bfrk[3][2];
      #pragma unroll
      for (int dw=0;dw<3;dw++)
        #pragma unroll
        for (int n=0;n<2;n++)
          bfrk[dw][n] = *(const bf16x8*)&wbase[(dw*32 + n*16 + l15)*64 + kh*32 + quad*8];
      #pragma unroll
      for (int dw=0; dw<3; dw++){
        bf16x8 afr[2];
        #pragma unroll
        for (int ms=0;ms<2;ms++)
          afr[ms] = *(const bf16x8*)&L[(ms*16 + l15 + dw)*72 + kh*32 + quad*8];
        #pragma unroll
        for (int n=0;n<2;n++)
          #pragma unroll
          for (int ms=0;ms<2;ms++)
            acc[n][ms] = __builtin_amdgcn_mfma_f32_16x16x32_bf16(afr[ms], bfrk[dw][n], acc[n][ms], 0,0,0);
      }
    }
  }

  // epilogue: D col(n)=lane&15 -> o, row(m)=quad*4+reg -> w (within half)
  #pragma unroll
  for (int n=0;n<2;n++){
    int o = n*16 + l15;
    if (o < 31){
      float bv = bias[h*31 + o];
      if (mode == 0){
        #pragma unroll
        for (int ms=0;ms<2;ms++){
          size_t base = (((size_t)b*31 + o)*64 + h)*64 + w0 + ms*16 + quad*4;
          #pragma unroll
          for (int reg=0;reg<4;reg++)
            outF[base + reg] = fmaxf(acc[n][ms][reg] + bv, 0.f);
        }
      } else {
        #pragma unroll
        for (int ms=0;ms<2;ms++){
          uint2 pw;
          pw.x = pk2(fmaxf(acc[n][ms][0] + bv, 0.f), fmaxf(acc[n][ms][1] + bv, 0.f));
          pw.y = pk2(fmaxf(acc[n][ms][2] + bv, 0.f), fmaxf(acc[n][ms][3] + bv, 0.f));
          *(uint2*)&outT[ (((size_t)b*31 + o)*64 + h)*64 + w0 + ms*16 + quad*4 ] = pw;
        }
      }
    }
  }
}

// ---------------- prep: spec weights -> GEMM-ready bf16 ----------------
__global__ __launch_bounds__(256) void k_prep(
    const float* __restrict__ We1a, const float* __restrict__ We2a,
    const float* __restrict__ We1b, const float* __restrict__ We2b,
    u16* __restrict__ waP, u16* __restrict__ wbP){
  int t = blockIdx.x*256 + threadIdx.x;
  if (t < 17856){
    int g = t/576, rem = t - g*576, dx = rem>>6, c = rem&63;
    int C; const float* wa;
    if (g==0)      { C=2; wa = We1a; }
    else if (g==30){ C=2; wa = We1a + 64*2*81; }
    else           { C=3; wa = We2a + (size_t)(g-1)*64*3*81; }
    const float* wrow = wa + (size_t)c*C*81;
    u16* dst = waP + ((size_t)(g*9 + dx)*64 + c)*40;
    int Kr = C*9;
    for (int k=0;k<40;k++){
      u16 v = 0;
      if (k < Kr) v = f2us(wrow[k*9 + dx]);
      dst[k] = v;
    }
  } else if (t < 17856 + 992){
    int u = t - 17856; int g = u>>5, c2 = u&31;
    const float* wb;
    if (g==0)      wb = We1b;
    else if (g==30) wb = We1b + 32*64;
    else            wb = We2b + (size_t)(g-1)*32*64;
    u16* dst = wbP + ((size_t)g*32 + c2)*72;
    for (int k=0;k<64;k++) dst[k] = f2us(wb[c2*64 + k]);
    for (int k=64;k<72;k++) dst[k] = 0;
  }
}

// ---------------- spectral a+b via MFMA (gl-batched) ----------------
// hb out (bf16): [gl][b][c2][y][x]
// B-fragments (waP/wbP) read straight from global (L2-hot) -> LDS = 36.9 KB overlay
__global__ __launch_bounds__(256) void k_spec_ab(
    const float* __restrict__ s3,
    const u16* __restrict__ waP, const u16* __restrict__ wbP,
    const float* __restrict__ be1a, const float* __restrict__ be1b,
    const float* __restrict__ be2a, const float* __restrict__ be2b,
    u16* __restrict__ hb, int g0){
  __shared__ __align__(16) unsigned char smem[36864];
  u16* colT = (u16*)smem;   // [4][72][40]  phase A (im2col input)
  u16* haT  = (u16*)smem;   // [256][72]    phase B (overlay after barrier)
  u16* hbL  = (u16*)smem;   // [32][296]    phase C (overlay after barrier)

  const int t = threadIdx.x;
  const int yo = blockIdx.x, b = blockIdx.y;
  const int gl = blockIdx.z;
  const int g  = g0 + gl;
  const int y0 = yo*4;
  const int wv = t>>6, lane = t&63, l15 = lane&15, quad = lane>>4;

  int C, cb; const float *ba, *bb;
  if (g==0)      { C=2; cb=0;  ba=be1a;           bb=be1b;        }
  else if (g==30){ C=2; cb=29; ba=be1a+64;        bb=be1b+32;     }
  else           { C=3; cb=g-1; ba=be2a+(size_t)(g-1)*64; bb=be2b+(size_t)(g-1)*32; }

  {
    uint4 z = {0,0,0,0};
    uint4* c4 = (uint4*)colT;
    #pragma unroll
    for (int j=0;j<6;j++){ int idx = j*256 + t; if (idx < 1440) c4[idx] = z; }
  }
  __syncthreads();

  // im2col scatter: yext lane-fastest so consecutive lanes store consecutive u16 (2-way, free)
  for (int idx=t; idx<576; idx+=256){
    int i = idx/192, rem = idx-192*i;
    int x4 = rem/12, yext = rem - x4*12;
    int yrow = y0 + yext - 4;
    if (i < C && yrow >= 0 && yrow < 64){
      float4 v = *(const float4*)&s3[ (((size_t)b*31 + cb + i)*64 + yrow)*64 + x4*4 ];
      u16 q0=f2us(v.x), q1=f2us(v.y), q2=f2us(v.z), q3=f2us(v.w);
      #pragma unroll
      for (int yl=0; yl<4; yl++){
        int dy = yext - yl;
        if (dy >= 0 && dy < 9){
          int k = i*9 + dy;
          int base = (yl*72 + x4*4 + 4)*40 + k;
          colT[base      ] = q0;
          colT[base + 40 ] = q1;
          colT[base + 80 ] = q2;
          colT[base + 120] = q3;
        }
      }
    }
  }
  __syncthreads();

  f32x4 acc[4][4];
  #pragma unroll
  for (int yl=0;yl<4;yl++)
    #pragma unroll
    for (int nf=0;nf<4;nf++) acc[yl][nf] = (f32x4){0.f,0.f,0.f,0.f};

  const u16* waPg = waP + (size_t)g*9*64*40;
  #pragma unroll
  for (int dx=0; dx<9; dx++){
    bf16x8 af[4];
    #pragma unroll
    for (int yl=0;yl<4;yl++)
      af[yl] = *(const bf16x8*)&colT[(yl*72 + wv*16 + l15 + dx)*40 + quad*8];
    #pragma unroll
    for (int nf=0;nf<4;nf++){
      bf16x8 bfr = *(const bf16x8*)&waPg[(dx*64 + nf*16 + l15)*40 + quad*8];
      #pragma unroll
      for (int yl=0;yl<4;yl++)
        acc[yl][nf] = __builtin_amdgcn_mfma_f32_16x16x32_bf16(af[yl], bfr, acc[yl][nf], 0,0,0);
    }
  }
  __syncthreads();   // colT dead -> haT may overlay

  #pragma unroll
  for (int nf=0;nf<4;nf++){
    float bav = ba[nf*16 + l15];
    #pragma unroll
    for (int yl=0;yl<4;yl++){
      int px = yl*64 + wv*16 + quad*4;
      #pragma unroll
      for (int reg=0;reg<4;reg++)
        haT[(px+reg)*72 + nf*16 + l15] = f2us(fmaxf(acc[yl][nf][reg] + bav, 0.f));
    }
  }
  __syncthreads();

  // preload all phase-B A fragments, then retire haT so hbL can overlay
  bf16x8 a2[2][4];
  #pragma unroll
  for (int kh=0; kh<2; kh++)
    #pragma unroll
    for (int j=0;j<4;j++)
      a2[kh][j] = *(const bf16x8*)&haT[((wv*4+j)*16 + l15)*72 + kh*32 + quad*8];
  __syncthreads();   // haT dead -> hbL may overlay

  const u16* wb_g = wbP + (size_t)g*32*72;
  f32x4 acc2[4][2];
  #pragma unroll
  for (int j=0;j<4;j++){ acc2[j][0] = (f32x4){0.f,0.f,0.f,0.f}; acc2[j][1] = (f32x4){0.f,0.f,0.f,0.f}; }
  #pragma unroll
  for (int kh=0; kh<2; kh++){
    #pragma unroll
    for (int nf=0;nf<2;nf++){
      bf16x8 b2 = *(const bf16x8*)&wb_g[(nf*16 + l15)*72 + kh*32 + quad*8];
      #pragma unroll
      for (int j=0;j<4;j++)
        acc2[j][nf] = __builtin_amdgcn_mfma_f32_16x16x32_bf16(a2[kh][j], b2, acc2[j][nf], 0,0,0);
    }
  }
  // packed uint2 stores, row stride 296 u16 (bank stride 20 -> ~2-way)
  #pragma unroll
  for (int nf=0;nf<2;nf++){
    float bbv = bb[nf*16 + l15];
    #pragma unroll
    for (int j=0;j<4;j++){
      int px = (wv*4+j)*16 + quad*4;
      uint2 pw;
      pw.x = pk2(fmaxf(acc2[j][nf][0] + bbv, 0.f), fmaxf(acc2[j][nf][1] + bbv, 0.f));
      pw.y = pk2(fmaxf(acc2[j][nf][2] + bbv, 0.f), fmaxf(acc2[j][nf][3] + bbv, 0.f));
      *(uint2*)&hbL[(nf*16+l15)*296 + px] = pw;
    }
  }
  __syncthreads();

  {
    int c2 = t>>3, xq = t&7;
    size_t base = (((size_t)gl*32 + b)*32 + c2)*4096 + (size_t)yo*256 + xq*32;
    #pragma unroll
    for (int q=0;q<4;q++)
      *(uint4*)&hb[base + q*8] = *(const uint4*)&hbL[c2*296 + xq*32 + q*8];
  }
}

// ---------------- spectral: 5x5 conv 32->1, writes rec f32 [g][b][y][x] ----------------
__global__ __launch_bounds__(256) void k_spec_c(
    const u16* __restrict__ hb, const float* __restrict__ We1c, const float* __restrict__ be1c,
    const float* __restrict__ We2c, const float* __restrict__ be2c,
    float* __restrict__ rec, int g0){
  __shared__ __align__(16) unsigned char smemC[58368 + 3200];
  u16*   hbT  = (u16*)smemC;                 // [32][12][76] bf16
  float* wcL  = (float*)(smemC + 58368);     // [32][25]
  float* redc = (float*)smemC;               // overlay after compute
  const int t  = threadIdx.x;
  const int y0 = blockIdx.x*8;
  const int b  = blockIdx.y;
  const int gl = blockIdx.z;
  const int g  = g0 + gl;
  const float *wc, *bc;
  if (g==0)      { wc = We1c;             bc = be1c;       }
  else if (g==30){ wc = We1c + 800;       bc = be1c + 1;   }
  else           { wc = We2c + (g-1)*800; bc = be2c + (g-1); }

  // vectorized halo staging: per (c2,row): 8x uint4 global loads, u32 LDS stores
  for (int idx=t; idx<384; idx+=256){
    int c2 = idx/12, row = idx - c2*12;
    u32* d32 = (u32*)&hbT[(size_t)(c2*12 + row)*76];
    d32[0]  = 0;   // cols 0,1
    d32[33] = 0;   // cols 66,67
    u32* di = d32 + 1;   // interior cols 2..65
    int yg = y0 - 2 + row;
    if (yg >= 0 && yg < 64){
      const uint4* srcp = (const uint4*)&hb[ (((size_t)gl*32 + b)*32 + c2)*4096 + (size_t)yg*64 ];
      #pragma unroll
      for (int q=0;q<8;q++){
        uint4 v = srcp[q];
        di[q*4+0]=v.x; di[q*4+1]=v.y; di[q*4+2]=v.z; di[q*4+3]=v.w;
      }
    } else {
      #pragma unroll
      for (int q=0;q<32;q++) di[q] = 0;
    }
  }
  for (int idx=t; idx<800; idx+=256) wcL[idx] = wc[idx];
  __syncthreads();

  const int xt = t&7, yq = (t>>3)&7, cqt = t>>6;
  const int x0 = xt*8;
  float acc[8];
  #pragma unroll
  for (int p=0;p<8;p++) acc[p]=0.f;
  for (int c2 = cqt*8; c2 < cqt*8+8; c2++){
    #pragma unroll
    for (int dy=0;dy<5;dy++){
      const uint2* hp = (const uint2*)&hbT[(c2*12 + yq+dy)*76 + x0];
      uint2 v0 = hp[0], v1 = hp[1], v2 = hp[2];
      float h[12];
      h[0]=lo2f(v0.x); h[1]=hi2f(v0.x); h[2]=lo2f(v0.y); h[3]=hi2f(v0.y);
      h[4]=lo2f(v1.x); h[5]=hi2f(v1.x); h[6]=lo2f(v1.y); h[7]=hi2f(v1.y);
      h[8]=lo2f(v2.x); h[9]=hi2f(v2.x); h[10]=lo2f(v2.y); h[11]=hi2f(v2.y);
      #pragma unroll
      for (int dx=0;dx<5;dx++){
        float wv = wcL[c2*25 + dy*5 + dx];
        #pragma unroll
        for (int p=0;p<8;p++) acc[p] = fmaf(h[p+dx], wv, acc[p]);
      }
    }
  }
  __syncthreads();
  int slot = yq*8 + xt;
  if (cqt >= 2){
    #pragma unroll
    for (int p=0;p<8;p++) redc[((cqt-2)*64 + slot)*8 + p] = acc[p];
  }
  __syncthreads();
  if (cqt < 2){
    #pragma unroll
    for (int p=0;p<8;p++) acc[p] += redc[(cqt*64 + slot)*8 + p];
  }
  __syncthreads();
  if (cqt == 1){
    #pragma unroll
    for (int p=0;p<8;p++) redc[slot*8 + p] = acc[p];
  }
  __syncthreads();
  if (cqt == 0){
    float bcv = bc[0];
    size_t base = (((size_t)g*32 + b)*64 + (y0+yq))*64 + x0;
    #pragma unroll
    for (int p=0;p<8;p++) rec[base+p] = acc[p] + redc[slot*8 + p] + bcv;
  }
}

// ---------------- final: out[b,y,x,o] = s3[b,o,y,x] + rec[o,b,y,x] (f32) ----------------
__global__ __launch_bounds__(256) void k_final(const float* __restrict__ s3,
        const float* __restrict__ rec, float* __restrict__ out){
  __shared__ float tile[31][65];
  const int t = threadIdx.x;
  const int y = blockIdx.x & 63;
  const int b = blockIdx.x >> 6;
  for (int idx=t; idx<1984; idx+=256){
    int o = idx>>6, x = idx&63;
    tile[o][x] = s3[ (((size_t)b*31+o)*64 + y)*64 + x ]
               + rec[ (((size_t)o*32+b)*64 + y)*64 + x ];
  }
  __syncthreads();
  size_t base = ((size_t)b*4096 + (size_t)y*64)*31;
  for (int idx=t; idx<1984; idx+=256){
    int x = idx/31, o = idx-31*x;
    out[base+idx] = tile[o][x];
  }
}

extern "C" void kernel_launch(void* const* d_in, const int* in_sizes, int n_in,
                              void* d_out, int out_size, void* d_ws, size_t ws_size,
                              hipStream_t stream){
  const float* x    = (const float*)d_in[0];
  const float* W1   = (const float*)d_in[1];
  const float* b1   = (const float*)d_in[2];
  const float* W2   = (const float*)d_in[3];
  const float* b2   = (const float*)d_in[4];
  const float* W3   = (const float*)d_in[5];
  const float* b3   = (const float*)d_in[6];
  const float* We1a = (const float*)d_in[7];
  const float* be1a = (const float*)d_in[8];
  const float* We1b = (const float*)d_in[9];
  const float* be1b = (const float*)d_in[10];
  const float* We1c = (const float*)d_in[11];
  const float* be1c = (const float*)d_in[12];
  const float* We2a = (const float*)d_in[13];
  const float* be2a = (const float*)d_in[14];
  const float* We2b = (const float*)d_in[15];
  const float* be2b = (const float*)d_in[16];
  const float* We2c = (const float*)d_in[17];
  const float* be2c = (const float*)d_in[18];
  float* out = (float*)d_out;

  // ws layout (time-multiplexed):
  //  spatial phase: s3 @0 (15.5M) | Wp @16M (<=24.4M) | xT @42M (0.5M)
  //  spec phase:    s3 @0         | rec @16M (15.5M)  | hb slabs @33030144 (8.39M each)
  char* ws = (char*)d_ws;
  float* s3  = (float*)(ws);
  u16*   Wp  = (u16*)(ws + 16777216);
  u16*   xT  = (u16*)(ws + 44040192);
  float* rec = (float*)(ws + 16777216);
  u16*   hb  = (u16*)(ws + 33030144);

  // d_out scratch (dead until k_final):
  //  spatial phase: bufA @0 (natural, 8.13M), bufB @8126464 (transposed, 8.13M)
  //  spec phase:    waP @0 (1.43M), wbP @1440000
  u16* bufA = (u16*)((char*)d_out);
  u16* bufB = (u16*)((char*)d_out + 8126464);
  u16* waP = (u16*)((char*)d_out);
  u16* wbP = (u16*)((char*)d_out + 1440000);

  dim3 bs(256);
  dim3 gsp(1024), gtr(32,31);
  k_prep_x<<<dim3(32),bs,0,stream>>>(x, xT);
  k_prep_w<<<dim3(64,1),bs,0,stream>>>(W1, Wp, 1);
  k_spatial2<<<gsp,bs,0,stream>>>(xT,  Wp, b1, nullptr, bufA, 1, 1);
  k_tr<<<gtr,bs,0,stream>>>(bufA, bufB);
  k_prep_w<<<dim3(64,31),bs,0,stream>>>(W2, Wp, 31);
  k_spatial2<<<gsp,bs,0,stream>>>(bufB, Wp, b2, nullptr, bufA, 31, 1);
  k_tr<<<gtr,bs,0,stream>>>(bufA, bufB);
  k_prep_w<<<dim3(64,31),bs,0,stream>>>(W3, Wp, 31);
  k_spatial2<<<gsp,bs,0,stream>>>(bufB, Wp, b3, s3, nullptr, 31, 0);

  k_prep<<<dim3(74),bs,0,stream>>>(We1a, We2a, We1b, We2b, waP, wbP);

  // gl batch: cap at 8 so hb slab (67 MB) stays L3-resident
  int batch = 8;
  if (ws_size > 33030144ull){
    size_t m = (ws_size - 33030144ull) / 8388608ull;
    if (m < 1) m = 1;
    if (m > 8) m = 8;
    batch = (int)m;
  }
  for (int g0=0; g0<31; g0+=batch){
    int c = 31 - g0; if (c > batch) c = batch;
    k_spec_ab<<<dim3(16,32,c),bs,0,stream>>>(s3, waP, wbP, be1a, be1b, be2a, be2b, hb, g0);
    k_spec_c <<<dim3(8,32,c),bs,0,stream>>>(hb, We1c,be1c,We2c,be2c, rec, g0);
  }
  k_final<<<dim3(2048),bs,0,stream>>>(s3, rec, out);
}

// Round 7
// 1039.683 us; speedup vs baseline: 1.0892x; 1.0892x over previous
//
#include <hip/hip_runtime.h>
#include <hip/hip_bf16.h>
#include <stdint.h>

typedef unsigned short u16;
typedef unsigned int   u32;
typedef __attribute__((ext_vector_type(8))) short bf16x8;
typedef __attribute__((ext_vector_type(4))) float f32x4;

__device__ __forceinline__ float us2f(u16 u){ return __uint_as_float(((u32)u)<<16); }
__device__ __forceinline__ float lo2f(u32 w){ return __uint_as_float(w<<16); }
__device__ __forceinline__ float hi2f(u32 w){ return __uint_as_float(w & 0xffff0000u); }
__device__ __forceinline__ u16 f2us(float f){
  u32 u = __float_as_uint(f);
  u32 r = (u + 0x7FFFu + ((u>>16)&1u)) >> 16;   // RNE
  return (u16)r;
}
__device__ __forceinline__ u32 pk2(float a, float b){ return (u32)f2us(a) | ((u32)f2us(b)<<16); }

// ---------------- prep: x (b,r,w) f32 -> xT[b][w][r] bf16 ----------------
__global__ __launch_bounds__(256) void k_prep_x(const float* __restrict__ x, u16* __restrict__ xT){
  __shared__ float tile[64][65];
  const int b = blockIdx.x, t = threadIdx.x;
  #pragma unroll
  for (int q=0;q<4;q++){
    int idx = q*256 + t, r = idx>>4, w4 = (idx&15)*4;
    float4 v = *(const float4*)&x[((size_t)b*64 + r)*64 + w4];
    tile[r][w4]=v.x; tile[r][w4+1]=v.y; tile[r][w4+2]=v.z; tile[r][w4+3]=v.w;
  }
  __syncthreads();
  #pragma unroll
  for (int q=0;q<2;q++){
    int idx = q*256 + t, w = idx>>3, rc = idx&7;
    uint4 o;
    o.x = pk2(tile[rc*8+0][w], tile[rc*8+1][w]);
    o.y = pk2(tile[rc*8+2][w], tile[rc*8+3][w]);
    o.z = pk2(tile[rc*8+4][w], tile[rc*8+5][w]);
    o.w = pk2(tile[rc*8+6][w], tile[rc*8+7][w]);
    *(uint4*)&xT[((size_t)b*64 + w)*64 + rc*8] = o;
  }
}

// ---------------- prep: W (64h,31o,CI,64r,3dw) f32 -> Wp[h][i][dw][o32][r64] bf16 ----------------
__global__ __launch_bounds__(256) void k_prep_w(const float* __restrict__ W,
        u16* __restrict__ Wp, int CI){
  __shared__ float rowW[5952];   // [o 31][j 192]
  const int h = blockIdx.x, i = blockIdx.y, t = threadIdx.x;
  for (int idx=t; idx<1488; idx+=256){
    int o = idx/48, j4 = (idx - o*48)*4;
    float4 v = *(const float4*)&W[ (((size_t)h*31 + o)*CI + i)*192 + j4 ];
    *(float4*)&rowW[o*192 + j4] = v;
  }
  __syncthreads();
  for (int idx=t; idx<768; idx+=256){
    int dw = idx>>8, rem = idx&255, o = rem>>3, rc = rem&7;
    uint4 ov = {0,0,0,0};
    if (o < 31){
      const float* s = &rowW[o*192 + dw];
      ov.x = pk2(s[(rc*8+0)*3], s[(rc*8+1)*3]);
      ov.y = pk2(s[(rc*8+2)*3], s[(rc*8+3)*3]);
      ov.z = pk2(s[(rc*8+4)*3], s[(rc*8+5)*3]);
      ov.w = pk2(s[(rc*8+6)*3], s[(rc*8+7)*3]);
    }
    *(uint4*)&Wp[ ((((size_t)h*CI + i)*3 + dw)*32 + o)*64 + rc*8 ] = ov;
  }
}

// ---------------- bf16 transpose: in[b][o][h][w] -> out[b][o][w][h] ----------------
__global__ __launch_bounds__(256) void k_tr(const u16* __restrict__ in, u16* __restrict__ outp){
  __shared__ u16 tile[64*72];
  const int b = blockIdx.x, o = blockIdx.y, t = threadIdx.x;
  const uint4* src = (const uint4*)(in + ((size_t)b*31 + o)*4096);
  #pragma unroll
  for (int q=0;q<2;q++){
    int idx = q*256 + t, hh = idx>>3, u = idx&7;
    *(uint4*)&tile[hh*72 + ((u ^ ((hh>>3)&7))*8)] = src[idx];
  }
  __syncthreads();
  u16* dst = outp + ((size_t)b*31 + o)*4096;
  #pragma unroll
  for (int q=0;q<2;q++){
    int idx = q*256 + t, w = idx>>3, hc = (idx&7)*8;
    u32 ow[4];
    #pragma unroll
    for (int j=0;j<4;j++){
      int h0 = hc + j*2, h1 = h0 + 1;
      u16 a = tile[h0*72 + (((w>>3) ^ ((h0>>3)&7))*8) + (w&7)];
      u16 bb= tile[h1*72 + (((w>>3) ^ ((h1>>3)&7))*8) + (w&7)];
      ow[j] = (u32)a | ((u32)bb<<16);
    }
    uint4 ov = {ow[0], ow[1], ow[2], ow[3]};
    *(uint4*)&dst[(size_t)w*64 + hc] = ov;
  }
}

// ---------------- spatial layer via MFMA, prepped inputs ----------------
// inT_g: [b][i][w][r] bf16 ; Wp: [h][i][dw][o32][r64] bf16 ; bias (64,31) f32
// mode 0: outF[b][o][h][w] f32 ; mode 1: outT[b][o][h][w] bf16 (natural; k_tr transposes)
// Block = 2h x 2b, 4 waves, full-w per wave. The two same-h waves issue IDENTICAL
// weight addresses -> one L2 fetch + L1 hit (12 KB/iter << 32 KB L1): halves weight
// L2 traffic vs round-5's 4h x 1b. Input staged to 2 shared slabs (dbuf, barrier).
// Pipeline: reg-prefetch input ch i+1 + weight frags i+1 (dbuf) + lgkm-only barrier.
// h tied to XCD (8 h per XCD -> 3 MB Wp slice L2-resident).
__global__ __launch_bounds__(256, 2) void k_spatial2(const u16* __restrict__ inT_g,
        const u16* __restrict__ Wp, const float* __restrict__ bias,
        float* __restrict__ outF, u16* __restrict__ outT, int CI, int mode){
  __shared__ __align__(16) u16 S[2][2][66*72];   // [bl][dbuf][wext 0..65][r pad72]
  const int t    = threadIdx.x;
  const int wv   = t>>6;
  const int lane = t&63;
  const int l15  = lane&15;
  const int quad = lane>>4;
  // 512 blocks = 8 xcd * (4 hq * 16 bg); waves: (hl, bl) = (wv&1, wv>>1)
  const int wg  = blockIdx.x;
  const int xcd = wg & 7;
  const int li  = wg >> 3;            // 0..63
  const int hq  = xcd*4 + (li>>4);    // 0..31
  const int bg  = li & 15;            // 0..15
  const int hl  = wv & 1;
  const int bl  = wv >> 1;
  const int h   = hq*2 + hl;
  const int b   = bg*2 + bl;

  // zero border rows (wext 0 and 65) of all 4 slabs: 72 uint4 total
  if (t < 72){
    int zbl = t/36, rem = t - zbl*36, zdb = rem/18, r2 = (rem%18)/9, j = rem%9;
    *(uint4*)&S[zbl][zdb][(r2 ? 65*72 : 0) + j*8] = (uint4){0,0,0,0};
  }

  f32x4 acc[2][4];
  #pragma unroll
  for (int n=0;n<2;n++)
    #pragma unroll
    for (int ms=0;ms<4;ms++) acc[n][ms] = (f32x4){0.f,0.f,0.f,0.f};

  const uint4* srcb0 = (const uint4*)(inT_g + (size_t)((bg*2+0)*CI)*4096);
  const uint4* srcb1 = (const uint4*)(inT_g + (size_t)((bg*2+1)*CI)*4096);
  const u16*   wrow  = Wp + (size_t)h*CI*3*32*64;

  // prologue: prefetch channel 0 of both b-slabs (4 uint4/thread) + channel-0 weights
  uint4 pf[4];
  #pragma unroll
  for (int k=0;k<4;k++){
    int u = k*256 + t;                       // 0..1023
    int sbl = u>>9, c = u&511;
    const uint4* src = sbl ? srcb1 : srcb0;
    pf[k] = src[c];
  }
  bf16x8 bA[2][3][2], bB[2][3][2];
  #pragma unroll
  for (int dw=0;dw<3;dw++)
    #pragma unroll
    for (int n=0;n<2;n++)
      #pragma unroll
      for (int kh=0;kh<2;kh++)
        bA[kh][dw][n] = *(const bf16x8*)&wrow[(dw*32 + n*16 + l15)*64 + kh*32 + quad*8];

  auto body = [&](bf16x8 (&bcur)[2][3][2], bf16x8 (&bnext)[2][3][2], int i){
    // write prefetched channel i into the two slabs (rows w=0..63 -> wext=1..64)
    #pragma unroll
    for (int k=0;k<4;k++){
      int u = k*256 + t, sbl = u>>9, c = u&511;
      int row = c>>3, cn = c&7;
      *(uint4*)&S[sbl][i&1][(row+1)*72 + cn*8] = pf[k];
    }
    // issue prefetches for channel i+1 (clamped; consumed next iteration)
    int inext = (i+1 < CI) ? (i+1) : (CI-1);
    #pragma unroll
    for (int k=0;k<4;k++){
      int u = k*256 + t, sbl = u>>9, c = u&511;
      const uint4* src = (sbl ? srcb1 : srcb0) + (size_t)inext*512;
      pf[k] = src[c];
    }
    const u16* wbase = wrow + (size_t)inext*6144;   // 3*32*64
    #pragma unroll
    for (int dw=0;dw<3;dw++)
      #pragma unroll
      for (int n=0;n<2;n++)
        #pragma unroll
        for (int kh=0;kh<2;kh++)
          bnext[kh][dw][n] = *(const bf16x8*)&wbase[(dw*32 + n*16 + l15)*64 + kh*32 + quad*8];
    // lgkm-only drain: ds_writes visible; vmcnt prefetches stay in flight
    asm volatile("s_waitcnt lgkmcnt(0)" ::: "memory");
    __builtin_amdgcn_s_barrier();
    __builtin_amdgcn_sched_barrier(0);
    const u16* L = S[bl][i&1];
    #pragma unroll
    for (int kh=0; kh<2; kh++){
      #pragma unroll
      for (int dw=0; dw<3; dw++){
        bf16x8 afr[4];
        #pragma unroll
        for (int ms=0;ms<4;ms++)
          afr[ms] = *(const bf16x8*)&L[(ms*16 + l15 + dw)*72 + kh*32 + quad*8];
        #pragma unroll
        for (int n=0;n<2;n++)
          #pragma unroll
          for (int ms=0;ms<4;ms++)
            acc[n][ms] = __builtin_amdgcn_mfma_f32_16x16x32_bf16(afr[ms], bcur[kh][dw][n], acc[n][ms], 0,0,0);
      }
    }
  };

  int i = 0;
  while (true){
    body(bA, bB, i); if (++i >= CI) break;
    body(bB, bA, i); if (++i >= CI) break;
  }

  // epilogue: D col(n)=lane&15 -> o, row(m)=quad*4+reg -> w ; NATURAL [b][o][h][w]
  #pragma unroll
  for (int n=0;n<2;n++){
    int o = n*16 + l15;
    if (o < 31){
      float bv = bias[h*31 + o];
      if (mode == 0){
        #pragma unroll
        for (int ms=0;ms<4;ms++){
          size_t base = (((size_t)b*31 + o)*64 + h)*64 + ms*16 + quad*4;
          #pragma unroll
          for (int reg=0;reg<4;reg++)
            outF[base + reg] = fmaxf(acc[n][ms][reg] + bv, 0.f);
        }
      } else {
        #pragma unroll
        for (int ms=0;ms<4;ms++){
          uint2 pw;
          pw.x = pk2(fmaxf(acc[n][ms][0] + bv, 0.f), fmaxf(acc[n][ms][1] + bv, 0.f));
          pw.y = pk2(fmaxf(acc[n][ms][2] + bv, 0.f), fmaxf(acc[n][ms][3] + bv, 0.f));
          *(uint2*)&outT[ (((size_t)b*31 + o)*64 + h)*64 + ms*16 + quad*4 ] = pw;
        }
      }
    }
  }
}

// ---------------- prep: spec weights -> GEMM-ready bf16 ----------------
__global__ __launch_bounds__(256) void k_prep(
    const float* __restrict__ We1a, const float* __restrict__ We2a,
    const float* __restrict__ We1b, const float* __restrict__ We2b,
    u16* __restrict__ waP, u16* __restrict__ wbP){
  int t = blockIdx.x*256 + threadIdx.x;
  if (t < 17856){
    int g = t/576, rem = t - g*576, dx = rem>>6, c = rem&63;
    int C; const float* wa;
    if (g==0)      { C=2; wa = We1a; }
    else if (g==30){ C=2; wa = We1a + 64*2*81; }
    else           { C=3; wa = We2a + (size_t)(g-1)*64*3*81; }
    const float* wrow = wa + (size_t)c*C*81;
    u16* dst = waP + ((size_t)(g*9 + dx)*64 + c)*40;
    int Kr = C*9;
    for (int k=0;k<40;k++){
      u16 v = 0;
      if (k < Kr) v = f2us(wrow[k*9 + dx]);
      dst[k] = v;
    }
  } else if (t < 17856 + 992){
    int u = t - 17856; int g = u>>5, c2 = u&31;
    const float* wb;
    if (g==0)      wb = We1b;
    else if (g==30) wb = We1b + 32*64;
    else            wb = We2b + (size_t)(g-1)*32*64;
    u16* dst = wbP + ((size_t)g*32 + c2)*72;
    for (int k=0;k<64;k++) dst[k] = f2us(wb[c2*64 + k]);
    for (int k=64;k<72;k++) dst[k] = 0;
  }
}

// ---------------- spectral a+b via MFMA (gl-batched) ----------------
__global__ __launch_bounds__(256) void k_spec_ab(
    const float* __restrict__ s3,
    const u16* __restrict__ waP, const u16* __restrict__ wbP,
    const float* __restrict__ be1a, const float* __restrict__ be1b,
    const float* __restrict__ be2a, const float* __restrict__ be2b,
    u16* __restrict__ hb, int g0){
  __shared__ __align__(16) unsigned char smem[36864];
  u16* colT = (u16*)smem;   // [4][72][40]  phase A (im2col input)
  u16* haT  = (u16*)smem;   // [256][72]    phase B (overlay after barrier)
  u16* hbL  = (u16*)smem;   // [32][296]    phase C (overlay after barrier)

  const int t = threadIdx.x;
  const int yo = blockIdx.x, b = blockIdx.y;
  const int gl = blockIdx.z;
  const int g  = g0 + gl;
  const int y0 = yo*4;
  const int wv = t>>6, lane = t&63, l15 = lane&15, quad = lane>>4;

  int C, cb; const float *ba, *bb;
  if (g==0)      { C=2; cb=0;  ba=be1a;           bb=be1b;        }
  else if (g==30){ C=2; cb=29; ba=be1a+64;        bb=be1b+32;     }
  else           { C=3; cb=g-1; ba=be2a+(size_t)(g-1)*64; bb=be2b+(size_t)(g-1)*32; }

  {
    uint4 z = {0,0,0,0};
    uint4* c4 = (uint4*)colT;
    #pragma unroll
    for (int j=0;j<6;j++){ int idx = j*256 + t; if (idx < 1440) c4[idx] = z; }
  }
  __syncthreads();

  // im2col scatter: yext lane-fastest so consecutive lanes store consecutive u16
  for (int idx=t; idx<576; idx+=256){
    int i = idx/192, rem = idx-192*i;
    int x4 = rem/12, yext = rem - x4*12;
    int yrow = y0 + yext - 4;
    if (i < C && yrow >= 0 && yrow < 64){
      float4 v = *(const float4*)&s3[ (((size_t)b*31 + cb + i)*64 + yrow)*64 + x4*4 ];
      u16 q0=f2us(v.x), q1=f2us(v.y), q2=f2us(v.z), q3=f2us(v.w);
      #pragma unroll
      for (int yl=0; yl<4; yl++){
        int dy = yext - yl;
        if (dy >= 0 && dy < 9){
          int k = i*9 + dy;
          int base = (yl*72 + x4*4 + 4)*40 + k;
          colT[base      ] = q0;
          colT[base + 40 ] = q1;
          colT[base + 80 ] = q2;
          colT[base + 120] = q3;
        }
      }
    }
  }
  __syncthreads();

  f32x4 acc[4][4];
  #pragma unroll
  for (int yl=0;yl<4;yl++)
    #pragma unroll
    for (int nf=0;nf<4;nf++) acc[yl][nf] = (f32x4){0.f,0.f,0.f,0.f};

  const u16* waPg = waP + (size_t)g*9*64*40;
  #pragma unroll
  for (int dx=0; dx<9; dx++){
    bf16x8 af[4];
    #pragma unroll
    for (int yl=0;yl<4;yl++)
      af[yl] = *(const bf16x8*)&colT[(yl*72 + wv*16 + l15 + dx)*40 + quad*8];
    #pragma unroll
    for (int nf=0;nf<4;nf++){
      bf16x8 bfr = *(const bf16x8*)&waPg[(dx*64 + nf*16 + l15)*40 + quad*8];
      #pragma unroll
      for (int yl=0;yl<4;yl++)
        acc[yl][nf] = __builtin_amdgcn_mfma_f32_16x16x32_bf16(af[yl], bfr, acc[yl][nf], 0,0,0);
    }
  }
  __syncthreads();   // colT dead -> haT may overlay

  #pragma unroll
  for (int nf=0;nf<4;nf++){
    float bav = ba[nf*16 + l15];
    #pragma unroll
    for (int yl=0;yl<4;yl++){
      int px = yl*64 + wv*16 + quad*4;
      #pragma unroll
      for (int reg=0;reg<4;reg++)
        haT[(px+reg)*72 + nf*16 + l15] = f2us(fmaxf(acc[yl][nf][reg] + bav, 0.f));
    }
  }
  __syncthreads();

  // preload all phase-B A fragments, then retire haT so hbL can overlay
  bf16x8 a2[2][4];
  #pragma unroll
  for (int kh=0; kh<2; kh++)
    #pragma unroll
    for (int j=0;j<4;j++)
      a2[kh][j] = *(const bf16x8*)&haT[((wv*4+j)*16 + l15)*72 + kh*32 + quad*8];
  __syncthreads();   // haT dead -> hbL may overlay

  const u16* wb_g = wbP + (size_t)g*32*72;
  f32x4 acc2[4][2];
  #pragma unroll
  for (int j=0;j<4;j++){ acc2[j][0] = (f32x4){0.f,0.f,0.f,0.f}; acc2[j][1] = (f32x4){0.f,0.f,0.f,0.f}; }
  #pragma unroll
  for (int kh=0; kh<2; kh++){
    #pragma unroll
    for (int nf=0;nf<2;nf++){
      bf16x8 b2 = *(const bf16x8*)&wb_g[(nf*16 + l15)*72 + kh*32 + quad*8];
      #pragma unroll
      for (int j=0;j<4;j++)
        acc2[j][nf] = __builtin_amdgcn_mfma_f32_16x16x32_bf16(a2[kh][j], b2, acc2[j][nf], 0,0,0);
    }
  }
  // packed uint2 stores, row stride 296 u16 (bank stride 20 -> ~2-way)
  #pragma unroll
  for (int nf=0;nf<2;nf++){
    float bbv = bb[nf*16 + l15];
    #pragma unroll
    for (int j=0;j<4;j++){
      int px = (wv*4+j)*16 + quad*4;
      uint2 pw;
      pw.x = pk2(fmaxf(acc2[j][nf][0] + bbv, 0.f), fmaxf(acc2[j][nf][1] + bbv, 0.f));
      pw.y = pk2(fmaxf(acc2[j][nf][2] + bbv, 0.f), fmaxf(acc2[j][nf][3] + bbv, 0.f));
      *(uint2*)&hbL[(nf*16+l15)*296 + px] = pw;
    }
  }
  __syncthreads();

  {
    int c2 = t>>3, xq = t&7;
    size_t base = (((size_t)gl*32 + b)*32 + c2)*4096 + (size_t)yo*256 + xq*32;
    #pragma unroll
    for (int q=0;q<4;q++)
      *(uint4*)&hb[base + q*8] = *(const uint4*)&hbL[c2*296 + xq*32 + q*8];
  }
}

// ---------------- spectral: 5x5 conv 32->1, writes rec f32 [g][b][y][x] ----------------
__global__ __launch_bounds__(256) void k_spec_c(
    const u16* __restrict__ hb, const float* __restrict__ We1c, const float* __restrict__ be1c,
    const float* __restrict__ We2c, const float* __restrict__ be2c,
    float* __restrict__ rec, int g0){
  __shared__ __align__(16) unsigned char smemC[58368 + 3200];
  u16*   hbT  = (u16*)smemC;                 // [32][12][76] bf16
  float* wcL  = (float*)(smemC + 58368);     // [32][25]
  float* redc = (float*)smemC;               // overlay after compute
  const int t  = threadIdx.x;
  const int y0 = blockIdx.x*8;
  const int b  = blockIdx.y;
  const int gl = blockIdx.z;
  const int g  = g0 + gl;
  const float *wc, *bc;
  if (g==0)      { wc = We1c;             bc = be1c;       }
  else if (g==30){ wc = We1c + 800;       bc = be1c + 1;   }
  else           { wc = We2c + (g-1)*800; bc = be2c + (g-1); }

  for (int idx=t; idx<384; idx+=256){
    int c2 = idx/12, row = idx - c2*12;
    u32* d32 = (u32*)&hbT[(size_t)(c2*12 + row)*76];
    d32[0]  = 0;
    d32[33] = 0;
    u32* di = d32 + 1;
    int yg = y0 - 2 + row;
    if (yg >= 0 && yg < 64){
      const uint4* srcp = (const uint4*)&hb[ (((size_t)gl*32 + b)*32 + c2)*4096 + (size_t)yg*64 ];
      #pragma unroll
      for (int q=0;q<8;q++){
        uint4 v = srcp[q];
        di[q*4+0]=v.x; di[q*4+1]=v.y; di[q*4+2]=v.z; di[q*4+3]=v.w;
      }
    } else {
      #pragma unroll
      for (int q=0;q<32;q++) di[q] = 0;
    }
  }
  for (int idx=t; idx<800; idx+=256) wcL[idx] = wc[idx];
  __syncthreads();

  const int xt = t&7, yq = (t>>3)&7, cqt = t>>6;
  const int x0 = xt*8;
  float acc[8];
  #pragma unroll
  for (int p=0;p<8;p++) acc[p]=0.f;
  for (int c2 = cqt*8; c2 < cqt*8+8; c2++){
    #pragma unroll
    for (int dy=0;dy<5;dy++){
      const uint2* hp = (const uint2*)&hbT[(c2*12 + yq+dy)*76 + x0];
      uint2 v0 = hp[0], v1 = hp[1], v2 = hp[2];
      float h[12];
      h[0]=lo2f(v0.x); h[1]=hi2f(v0.x); h[2]=lo2f(v0.y); h[3]=hi2f(v0.y);
      h[4]=lo2f(v1.x); h[5]=hi2f(v1.x); h[6]=lo2f(v1.y); h[7]=hi2f(v1.y);
      h[8]=lo2f(v2.x); h[9]=hi2f(v2.x); h[10]=lo2f(v2.y); h[11]=hi2f(v2.y);
      #pragma unroll
      for (int dx=0;dx<5;dx++){
        float wv = wcL[c2*25 + dy*5 + dx];
        #pragma unroll
        for (int p=0;p<8;p++) acc[p] = fmaf(h[p+dx], wv, acc[p]);
      }
    }
  }
  __syncthreads();
  int slot = yq*8 + xt;
  if (cqt >= 2){
    #pragma unroll
    for (int p=0;p<8;p++) redc[((cqt-2)*64 + slot)*8 + p] = acc[p];
  }
  __syncthreads();
  if (cqt < 2){
    #pragma unroll
    for (int p=0;p<8;p++) acc[p] += redc[(cqt*64 + slot)*8 + p];
  }
  __syncthreads();
  if (cqt == 1){
    #pragma unroll
    for (int p=0;p<8;p++) redc[slot*8 + p] = acc[p];
  }
  __syncthreads();
  if (cqt == 0){
    float bcv = bc[0];
    size_t base = (((size_t)g*32 + b)*64 + (y0+yq))*64 + x0;
    #pragma unroll
    for (int p=0;p<8;p++) rec[base+p] = acc[p] + redc[slot*8 + p] + bcv;
  }
}

// ---------------- final: out[b,y,x,o] = s3[b,o,y,x] + rec[o,b,y,x] (f32) ----------------
__global__ __launch_bounds__(256) void k_final(const float* __restrict__ s3,
        const float* __restrict__ rec, float* __restrict__ out){
  __shared__ float tile[31][65];
  const int t = threadIdx.x;
  const int y = blockIdx.x & 63;
  const int b = blockIdx.x >> 6;
  for (int idx=t; idx<1984; idx+=256){
    int o = idx>>6, x = idx&63;
    tile[o][x] = s3[ (((size_t)b*31+o)*64 + y)*64 + x ]
               + rec[ (((size_t)o*32+b)*64 + y)*64 + x ];
  }
  __syncthreads();
  size_t base = ((size_t)b*4096 + (size_t)y*64)*31;
  for (int idx=t; idx<1984; idx+=256){
    int x = idx/31, o = idx-31*x;
    out[base+idx] = tile[o][x];
  }
}

extern "C" void kernel_launch(void* const* d_in, const int* in_sizes, int n_in,
                              void* d_out, int out_size, void* d_ws, size_t ws_size,
                              hipStream_t stream){
  const float* x    = (const float*)d_in[0];
  const float* W1   = (const float*)d_in[1];
  const float* b1   = (const float*)d_in[2];
  const float* W2   = (const float*)d_in[3];
  const float* b2   = (const float*)d_in[4];
  const float* W3   = (const float*)d_in[5];
  const float* b3   = (const float*)d_in[6];
  const float* We1a = (const float*)d_in[7];
  const float* be1a = (const float*)d_in[8];
  const float* We1b = (const float*)d_in[9];
  const float* be1b = (const float*)d_in[10];
  const float* We1c = (const float*)d_in[11];
  const float* be1c = (const float*)d_in[12];
  const float* We2a = (const float*)d_in[13];
  const float* be2a = (const float*)d_in[14];
  const float* We2b = (const float*)d_in[15];
  const float* be2b = (const float*)d_in[16];
  const float* We2c = (const float*)d_in[17];
  const float* be2c = (const float*)d_in[18];
  float* out = (float*)d_out;

  // ws layout (time-multiplexed):
  //  spatial phase: s3 @0 (15.5M) | Wp @16M (<=24.4M) | xT @42M (0.5M)
  //  spec phase:    s3 @0         | rec @16M (15.5M)  | hb slabs @33030144 (8.39M each)
  char* ws = (char*)d_ws;
  float* s3  = (float*)(ws);
  u16*   Wp  = (u16*)(ws + 16777216);
  u16*   xT  = (u16*)(ws + 44040192);
  float* rec = (float*)(ws + 16777216);
  u16*   hb  = (u16*)(ws + 33030144);

  // d_out scratch (dead until k_final):
  //  spatial phase: bufA @0 (natural, 8.13M), bufB @8126464 (transposed, 8.13M)
  //  spec phase:    waP @0 (1.43M), wbP @1440000
  u16* bufA = (u16*)((char*)d_out);
  u16* bufB = (u16*)((char*)d_out + 8126464);
  u16* waP = (u16*)((char*)d_out);
  u16* wbP = (u16*)((char*)d_out + 1440000);

  dim3 bs(256);
  dim3 gsp(512), gtr(32,31);
  k_prep_x<<<dim3(32),bs,0,stream>>>(x, xT);
  k_prep_w<<<dim3(64,1),bs,0,stream>>>(W1, Wp, 1);
  k_spatial2<<<gsp,bs,0,stream>>>(xT,  Wp, b1, nullptr, bufA, 1, 1);
  k_tr<<<gtr,bs,0,stream>>>(bufA, bufB);
  k_prep_w<<<dim3(64,31),bs,0,stream>>>(W2, Wp, 31);
  k_spatial2<<<gsp,bs,0,stream>>>(bufB, Wp, b2, nullptr, bufA, 31, 1);
  k_tr<<<gtr,bs,0,stream>>>(bufA, bufB);
  k_prep_w<<<dim3(64,31),bs,0,stream>>>(W3, Wp, 31);
  k_spatial2<<<gsp,bs,0,stream>>>(bufB, Wp, b3, s3, nullptr, 31, 0);

  k_prep<<<dim3(74),bs,0,stream>>>(We1a, We2a, We1b, We2b, waP, wbP);

  // gl batch: cap at 8 so hb slab (67 MB) stays L3-resident
  int batch = 8;
  if (ws_size > 33030144ull){
    size_t m = (ws_size - 33030144ull) / 8388608ull;
    if (m < 1) m = 1;
    if (m > 8) m = 8;
    batch = (int)m;
  }
  for (int g0=0; g0<31; g0+=batch){
    int c = 31 - g0; if (c > batch) c = batch;
    k_spec_ab<<<dim3(16,32,c),bs,0,stream>>>(s3, waP, wbP, be1a, be1b, be2a, be2b, hb, g0);
    k_spec_c <<<dim3(8,32,c),bs,0,stream>>>(hb, We1c,be1c,We2c,be2c, rec, g0);
  }
  k_final<<<dim3(2048),bs,0,stream>>>(s3, rec, out);
}

// Round 8
// 986.526 us; speedup vs baseline: 1.1479x; 1.0539x over previous
//
#include <hip/hip_runtime.h>
#include <hip/hip_bf16.h>
#include <stdint.h>

typedef unsigned short u16;
typedef unsigned int   u32;
typedef __attribute__((ext_vector_type(8))) short bf16x8;
typedef __attribute__((ext_vector_type(4))) float f32x4;

__device__ __forceinline__ float us2f(u16 u){ return __uint_as_float(((u32)u)<<16); }
__device__ __forceinline__ float lo2f(u32 w){ return __uint_as_float(w<<16); }
__device__ __forceinline__ float hi2f(u32 w){ return __uint_as_float(w & 0xffff0000u); }
__device__ __forceinline__ u16 f2us(float f){
  u32 u = __float_as_uint(f);
  u32 r = (u + 0x7FFFu + ((u>>16)&1u)) >> 16;   // RNE
  return (u16)r;
}
__device__ __forceinline__ u32 pk2(float a, float b){ return (u32)f2us(a) | ((u32)f2us(b)<<16); }

// ---------------- prep: x (b,r,w) f32 -> xT[b][w][r] bf16 ----------------
__global__ __launch_bounds__(256) void k_prep_x(const float* __restrict__ x, u16* __restrict__ xT){
  __shared__ float tile[64][65];
  const int b = blockIdx.x, t = threadIdx.x;
  #pragma unroll
  for (int q=0;q<4;q++){
    int idx = q*256 + t, r = idx>>4, w4 = (idx&15)*4;
    float4 v = *(const float4*)&x[((size_t)b*64 + r)*64 + w4];
    tile[r][w4]=v.x; tile[r][w4+1]=v.y; tile[r][w4+2]=v.z; tile[r][w4+3]=v.w;
  }
  __syncthreads();
  #pragma unroll
  for (int q=0;q<2;q++){
    int idx = q*256 + t, w = idx>>3, rc = idx&7;
    uint4 o;
    o.x = pk2(tile[rc*8+0][w], tile[rc*8+1][w]);
    o.y = pk2(tile[rc*8+2][w], tile[rc*8+3][w]);
    o.z = pk2(tile[rc*8+4][w], tile[rc*8+5][w]);
    o.w = pk2(tile[rc*8+6][w], tile[rc*8+7][w]);
    *(uint4*)&xT[((size_t)b*64 + w)*64 + rc*8] = o;
  }
}

// ---------------- prep: W (64h,31o,CI,64r,3dw) f32 -> Wp[h][i][dw][o32][r64] bf16 ----------------
__global__ __launch_bounds__(256) void k_prep_w(const float* __restrict__ W,
        u16* __restrict__ Wp, int CI){
  __shared__ float rowW[5952];   // [o 31][j 192]
  const int h = blockIdx.x, i = blockIdx.y, t = threadIdx.x;
  for (int idx=t; idx<1488; idx+=256){
    int o = idx/48, j4 = (idx - o*48)*4;
    float4 v = *(const float4*)&W[ (((size_t)h*31 + o)*CI + i)*192 + j4 ];
    *(float4*)&rowW[o*192 + j4] = v;
  }
  __syncthreads();
  for (int idx=t; idx<768; idx+=256){
    int dw = idx>>8, rem = idx&255, o = rem>>3, rc = rem&7;
    uint4 ov = {0,0,0,0};
    if (o < 31){
      const float* s = &rowW[o*192 + dw];
      ov.x = pk2(s[(rc*8+0)*3], s[(rc*8+1)*3]);
      ov.y = pk2(s[(rc*8+2)*3], s[(rc*8+3)*3]);
      ov.z = pk2(s[(rc*8+4)*3], s[(rc*8+5)*3]);
      ov.w = pk2(s[(rc*8+6)*3], s[(rc*8+7)*3]);
    }
    *(uint4*)&Wp[ ((((size_t)h*CI + i)*3 + dw)*32 + o)*64 + rc*8 ] = ov;
  }
}

// ---------------- bf16 transpose: in[b][o][h][w] -> out[b][o][w][h] ----------------
__global__ __launch_bounds__(256) void k_tr(const u16* __restrict__ in, u16* __restrict__ outp){
  __shared__ u16 tile[64*72];
  const int b = blockIdx.x, o = blockIdx.y, t = threadIdx.x;
  const uint4* src = (const uint4*)(in + ((size_t)b*31 + o)*4096);
  #pragma unroll
  for (int q=0;q<2;q++){
    int idx = q*256 + t, hh = idx>>3, u = idx&7;
    *(uint4*)&tile[hh*72 + ((u ^ ((hh>>3)&7))*8)] = src[idx];
  }
  __syncthreads();
  u16* dst = outp + ((size_t)b*31 + o)*4096;
  #pragma unroll
  for (int q=0;q<2;q++){
    int idx = q*256 + t, w = idx>>3, hc = (idx&7)*8;
    u32 ow[4];
    #pragma unroll
    for (int j=0;j<4;j++){
      int h0 = hc + j*2, h1 = h0 + 1;
      u16 a = tile[h0*72 + (((w>>3) ^ ((h0>>3)&7))*8) + (w&7)];
      u16 bb= tile[h1*72 + (((w>>3) ^ ((h1>>3)&7))*8) + (w&7)];
      ow[j] = (u32)a | ((u32)bb<<16);
    }
    uint4 ov = {ow[0], ow[1], ow[2], ow[3]};
    *(uint4*)&dst[(size_t)w*64 + hc] = ov;
  }
}

// ---------------- spatial layer via MFMA, prepped inputs (round-5 proven config) ----------------
// inT_g: [b][i][w][r] bf16 ; Wp: [h][i][dw][o32][r64] bf16 ; bias (64,31) f32
// mode 0: outF[b][o][h][w] f32 ; mode 1: outT[b][o][h][w] bf16 (natural; k_tr transposes)
// 256 threads (4 waves = 4 h), full-w tile. Grid 512, hg tied to XCD (8 h -> 3 MB Wp
// slice L2-resident). Pipeline: reg-prefetch input ch i+1 + weight frags i+1 (dbuf)
// + lgkm-only barrier (vmcnt prefetches stay in flight).
__global__ __launch_bounds__(256) void k_spatial2(const u16* __restrict__ inT_g,
        const u16* __restrict__ Wp, const float* __restrict__ bias,
        float* __restrict__ outF, u16* __restrict__ outT, int CI, int mode){
  __shared__ __align__(16) u16 inT[2][66*72];   // [wext 0..65][r pad72], rows 0/65 zero
  const int t    = threadIdx.x;
  const int wv   = t>>6;
  const int lane = t&63;
  const int l15  = lane&15;
  const int quad = lane>>4;
  // 512 blocks = 8 xcd * (2 hg * 32 b): hg tied to xcd -> per-XCD Wp slice 3 MB
  const int wg  = blockIdx.x;
  const int xcd = wg & 7;
  const int li  = wg >> 3;
  const int hg  = xcd*2 + (li>>5);
  const int b   = li & 31;
  const int h   = hg*4 + wv;

  if (t < 72){
    inT[0][t] = 0; inT[0][65*72 + t] = 0;
    inT[1][t] = 0; inT[1][65*72 + t] = 0;
  }

  f32x4 acc[2][4];
  #pragma unroll
  for (int n=0;n<2;n++)
    #pragma unroll
    for (int ms=0;ms<4;ms++) acc[n][ms] = (f32x4){0.f,0.f,0.f,0.f};

  const uint4* srcb = (const uint4*)(inT_g + (size_t)b*CI*4096);
  const u16*   wrow = Wp + (size_t)h*CI*3*32*64;

  // prologue: prefetch channel 0 input + channel 0 weight fragments
  uint4 pf[2];
  #pragma unroll
  for (int q=0;q<2;q++) pf[q] = srcb[q*256 + t];
  bf16x8 bA[2][3][2], bB[2][3][2];
  #pragma unroll
  for (int dw=0;dw<3;dw++)
    #pragma unroll
    for (int n=0;n<2;n++)
      #pragma unroll
      for (int kh=0;kh<2;kh++)
        bA[kh][dw][n] = *(const bf16x8*)&wrow[(dw*32 + n*16 + l15)*64 + kh*32 + quad*8];

  auto body = [&](bf16x8 (&bcur)[2][3][2], bf16x8 (&bnext)[2][3][2], int i){
    u16* L = inT[i&1];
    // write prefetched channel i into LDS (rows w=0..63 -> wext=1..64)
    #pragma unroll
    for (int q=0;q<2;q++){
      int idx = q*256 + t, row = idx>>3, ch = idx&7;
      *(uint4*)&L[(row+1)*72 + ch*8] = pf[q];
    }
    // issue prefetches for channel i+1 (clamped; consumed next iteration)
    int inext = (i+1 < CI) ? (i+1) : (CI-1);
    const uint4* src = srcb + (size_t)inext*512;
    #pragma unroll
    for (int q=0;q<2;q++) pf[q] = src[q*256 + t];
    const u16* wbase = wrow + (size_t)inext*6144;   // 3*32*64
    #pragma unroll
    for (int dw=0;dw<3;dw++)
      #pragma unroll
      for (int n=0;n<2;n++)
        #pragma unroll
        for (int kh=0;kh<2;kh++)
          bnext[kh][dw][n] = *(const bf16x8*)&wbase[(dw*32 + n*16 + l15)*64 + kh*32 + quad*8];
    // lgkm-only drain: ds_writes visible; vmcnt prefetches stay in flight
    asm volatile("s_waitcnt lgkmcnt(0)" ::: "memory");
    __builtin_amdgcn_s_barrier();
    __builtin_amdgcn_sched_barrier(0);
    #pragma unroll
    for (int kh=0; kh<2; kh++){
      #pragma unroll
      for (int dw=0; dw<3; dw++){
        bf16x8 afr[4];
        #pragma unroll
        for (int ms=0;ms<4;ms++)
          afr[ms] = *(const bf16x8*)&L[(ms*16 + l15 + dw)*72 + kh*32 + quad*8];
        #pragma unroll
        for (int n=0;n<2;n++)
          #pragma unroll
          for (int ms=0;ms<4;ms++)
            acc[n][ms] = __builtin_amdgcn_mfma_f32_16x16x32_bf16(afr[ms], bcur[kh][dw][n], acc[n][ms], 0,0,0);
      }
    }
  };

  int i = 0;
  while (true){
    body(bA, bB, i); if (++i >= CI) break;
    body(bB, bA, i); if (++i >= CI) break;
  }

  // epilogue: D col(n)=lane&15 -> o, row(m)=quad*4+reg -> w ; NATURAL [b][o][h][w]
  #pragma unroll
  for (int n=0;n<2;n++){
    int o = n*16 + l15;
    if (o < 31){
      float bv = bias[h*31 + o];
      if (mode == 0){
        #pragma unroll
        for (int ms=0;ms<4;ms++){
          size_t base = (((size_t)b*31 + o)*64 + h)*64 + ms*16 + quad*4;
          #pragma unroll
          for (int reg=0;reg<4;reg++)
            outF[base + reg] = fmaxf(acc[n][ms][reg] + bv, 0.f);
        }
      } else {
        #pragma unroll
        for (int ms=0;ms<4;ms++){
          uint2 pw;
          pw.x = pk2(fmaxf(acc[n][ms][0] + bv, 0.f), fmaxf(acc[n][ms][1] + bv, 0.f));
          pw.y = pk2(fmaxf(acc[n][ms][2] + bv, 0.f), fmaxf(acc[n][ms][3] + bv, 0.f));
          *(uint2*)&outT[ (((size_t)b*31 + o)*64 + h)*64 + ms*16 + quad*4 ] = pw;
        }
      }
    }
  }
}

// ---------------- prep: spec weights -> GEMM-ready bf16 ----------------
__global__ __launch_bounds__(256) void k_prep(
    const float* __restrict__ We1a, const float* __restrict__ We2a,
    const float* __restrict__ We1b, const float* __restrict__ We2b,
    u16* __restrict__ waP, u16* __restrict__ wbP){
  int t = blockIdx.x*256 + threadIdx.x;
  if (t < 17856){
    int g = t/576, rem = t - g*576, dx = rem>>6, c = rem&63;
    int C; const float* wa;
    if (g==0)      { C=2; wa = We1a; }
    else if (g==30){ C=2; wa = We1a + 64*2*81; }
    else           { C=3; wa = We2a + (size_t)(g-1)*64*3*81; }
    const float* wrow = wa + (size_t)c*C*81;
    u16* dst = waP + ((size_t)(g*9 + dx)*64 + c)*40;
    int Kr = C*9;
    for (int k=0;k<40;k++){
      u16 v = 0;
      if (k < Kr) v = f2us(wrow[k*9 + dx]);
      dst[k] = v;
    }
  } else if (t < 17856 + 992){
    int u = t - 17856; int g = u>>5, c2 = u&31;
    const float* wb;
    if (g==0)      wb = We1b;
    else if (g==30) wb = We1b + 32*64;
    else            wb = We2b + (size_t)(g-1)*32*64;
    u16* dst = wbP + ((size_t)g*32 + c2)*72;
    for (int k=0;k<64;k++) dst[k] = f2us(wb[c2*64 + k]);
    for (int k=64;k<72;k++) dst[k] = 0;
  }
}

// ---------------- spectral a+b via MFMA (gl-batched) ----------------
// hb out (bf16): [gl][b][c2][y][x]
// Phase A rebuilt as stage-then-gather: s3 rows staged ONCE as bf16 (1/3 the global
// traffic of the old per-yl scatter), then a dense conflict-free gather fills colT.
__global__ __launch_bounds__(256) void k_spec_ab(
    const float* __restrict__ s3,
    const u16* __restrict__ waP, const u16* __restrict__ wbP,
    const float* __restrict__ be1a, const float* __restrict__ be1b,
    const float* __restrict__ be2a, const float* __restrict__ be2b,
    u16* __restrict__ hb, int g0){
  __shared__ __align__(16) unsigned char smem[36864];
  u16* colT  = (u16*)smem;            // [4][72][40]   phase A (im2col input), 23040 B
  u16* stage = (u16*)(smem + 23040);  // [3][12][64]   phase A s3 row stage, 4608 B
  u16* haT   = (u16*)smem;            // [256][72]     phase B (overlay after barrier)
  u16* hbL   = (u16*)smem;            // [32][296]     phase C (overlay after barrier)

  const int t = threadIdx.x;
  const int yo = blockIdx.x, b = blockIdx.y;
  const int gl = blockIdx.z;
  const int g  = g0 + gl;
  const int y0 = yo*4;
  const int wv = t>>6, lane = t&63, l15 = lane&15, quad = lane>>4;

  int C, cb; const float *ba, *bb;
  if (g==0)      { C=2; cb=0;  ba=be1a;           bb=be1b;        }
  else if (g==30){ C=2; cb=29; ba=be1a+64;        bb=be1b+32;     }
  else           { C=3; cb=g-1; ba=be2a+(size_t)(g-1)*64; bb=be2b+(size_t)(g-1)*32; }

  // A1: x-pad zero (colT cols 0..3, 68..71) + bf16 row stage (12 yext rows, once)
  if (t < 160){
    int yl = t/40, rem = t - yl*40, xi = rem/5, q = rem - xi*5;
    int xc = (xi < 4) ? xi : xi + 64;
    *(uint4*)&colT[(yl*72 + xc)*40 + q*8] = (uint4){0,0,0,0};
  }
  for (int idx=t; idx<576; idx+=256){
    int i = idx/192, rem = idx-192*i, yext = rem>>4, x4 = rem&15;
    int yrow = y0 + yext - 4;
    uint2 sv = {0,0};
    if (i < C && yrow >= 0 && yrow < 64){
      float4 v = *(const float4*)&s3[ (((size_t)b*31 + cb + i)*64 + yrow)*64 + x4*4 ];
      sv.x = pk2(v.x, v.y);
      sv.y = pk2(v.z, v.w);
    }
    *(uint2*)&stage[(i*12 + yext)*64 + x4*4] = sv;
  }
  __syncthreads();

  // A2: dense gather -> colT[(yl*72 + x + 4)*40 + k], exactly 1 px per thread
  {
    const int yl = t>>6, x = t&63;
    const int C9 = C*9;
    u32 wbuf[20];
    #pragma unroll
    for (int kk=0;kk<20;kk++){
      int k0 = kk*2, k1 = kk*2+1;
      int i0 = k0/9, dy0 = k0 - i0*9;
      int i1 = k1/9, dy1 = k1 - i1*9;
      int ii0 = (k0 < C9) ? i0 : 0;
      int ii1 = (k1 < C9) ? i1 : 0;
      u32 v0 = (k0 < C9) ? (u32)stage[(ii0*12 + (yl+dy0))*64 + x] : 0u;
      u32 v1 = (k1 < C9) ? (u32)stage[(ii1*12 + (yl+dy1))*64 + x] : 0u;
      wbuf[kk] = v0 | (v1<<16);
    }
    u16* dst = &colT[(yl*72 + x + 4)*40];
    #pragma unroll
    for (int q=0;q<5;q++){
      uint4 ov = { wbuf[q*4], wbuf[q*4+1], wbuf[q*4+2], wbuf[q*4+3] };
      *(uint4*)&dst[q*8] = ov;
    }
  }
  __syncthreads();

  f32x4 acc[4][4];
  #pragma unroll
  for (int yl=0;yl<4;yl++)
    #pragma unroll
    for (int nf=0;nf<4;nf++) acc[yl][nf] = (f32x4){0.f,0.f,0.f,0.f};

  const u16* waPg = waP + (size_t)g*9*64*40;
  #pragma unroll
  for (int dx=0; dx<9; dx++){
    bf16x8 af[4];
    #pragma unroll
    for (int yl=0;yl<4;yl++)
      af[yl] = *(const bf16x8*)&colT[(yl*72 + wv*16 + l15 + dx)*40 + quad*8];
    #pragma unroll
    for (int nf=0;nf<4;nf++){
      bf16x8 bfr = *(const bf16x8*)&waPg[(dx*64 + nf*16 + l15)*40 + quad*8];
      #pragma unroll
      for (int yl=0;yl<4;yl++)
        acc[yl][nf] = __builtin_amdgcn_mfma_f32_16x16x32_bf16(af[yl], bfr, acc[yl][nf], 0,0,0);
    }
  }
  __syncthreads();   // colT/stage dead -> haT may overlay

  #pragma unroll
  for (int nf=0;nf<4;nf++){
    float bav = ba[nf*16 + l15];
    #pragma unroll
    for (int yl=0;yl<4;yl++){
      int px = yl*64 + wv*16 + quad*4;
      #pragma unroll
      for (int reg=0;reg<4;reg++)
        haT[(px+reg)*72 + nf*16 + l15] = f2us(fmaxf(acc[yl][nf][reg] + bav, 0.f));
    }
  }
  __syncthreads();

  // preload all phase-B A fragments, then retire haT so hbL can overlay
  bf16x8 a2[2][4];
  #pragma unroll
  for (int kh=0; kh<2; kh++)
    #pragma unroll
    for (int j=0;j<4;j++)
      a2[kh][j] = *(const bf16x8*)&haT[((wv*4+j)*16 + l15)*72 + kh*32 + quad*8];
  __syncthreads();   // haT dead -> hbL may overlay

  const u16* wb_g = wbP + (size_t)g*32*72;
  f32x4 acc2[4][2];
  #pragma unroll
  for (int j=0;j<4;j++){ acc2[j][0] = (f32x4){0.f,0.f,0.f,0.f}; acc2[j][1] = (f32x4){0.f,0.f,0.f,0.f}; }
  #pragma unroll
  for (int kh=0; kh<2; kh++){
    #pragma unroll
    for (int nf=0;nf<2;nf++){
      bf16x8 b2 = *(const bf16x8*)&wb_g[(nf*16 + l15)*72 + kh*32 + quad*8];
      #pragma unroll
      for (int j=0;j<4;j++)
        acc2[j][nf] = __builtin_amdgcn_mfma_f32_16x16x32_bf16(a2[kh][j], b2, acc2[j][nf], 0,0,0);
    }
  }
  // packed uint2 stores, row stride 296 u16 (bank stride 20 -> ~2-way)
  #pragma unroll
  for (int nf=0;nf<2;nf++){
    float bbv = bb[nf*16 + l15];
    #pragma unroll
    for (int j=0;j<4;j++){
      int px = (wv*4+j)*16 + quad*4;
      uint2 pw;
      pw.x = pk2(fmaxf(acc2[j][nf][0] + bbv, 0.f), fmaxf(acc2[j][nf][1] + bbv, 0.f));
      pw.y = pk2(fmaxf(acc2[j][nf][2] + bbv, 0.f), fmaxf(acc2[j][nf][3] + bbv, 0.f));
      *(uint2*)&hbL[(nf*16+l15)*296 + px] = pw;
    }
  }
  __syncthreads();

  {
    int c2 = t>>3, xq = t&7;
    size_t base = (((size_t)gl*32 + b)*32 + c2)*4096 + (size_t)yo*256 + xq*32;
    #pragma unroll
    for (int q=0;q<4;q++)
      *(uint4*)&hb[base + q*8] = *(const uint4*)&hbL[c2*296 + xq*32 + q*8];
  }
}

// ---------------- spectral: 5x5 conv 32->1, writes rec f32 [g][b][y][x] ----------------
__global__ __launch_bounds__(256) void k_spec_c(
    const u16* __restrict__ hb, const float* __restrict__ We1c, const float* __restrict__ be1c,
    const float* __restrict__ We2c, const float* __restrict__ be2c,
    float* __restrict__ rec, int g0){
  __shared__ __align__(16) unsigned char smemC[58368 + 3200];
  u16*   hbT  = (u16*)smemC;                 // [32][12][76] bf16
  float* wcL  = (float*)(smemC + 58368);     // [32][25]
  float* redc = (float*)smemC;               // overlay after compute
  const int t  = threadIdx.x;
  const int y0 = blockIdx.x*8;
  const int b  = blockIdx.y;
  const int gl = blockIdx.z;
  const int g  = g0 + gl;
  const float *wc, *bc;
  if (g==0)      { wc = We1c;             bc = be1c;       }
  else if (g==30){ wc = We1c + 800;       bc = be1c + 1;   }
  else           { wc = We2c + (g-1)*800; bc = be2c + (g-1); }

  for (int idx=t; idx<384; idx+=256){
    int c2 = idx/12, row = idx - c2*12;
    u32* d32 = (u32*)&hbT[(size_t)(c2*12 + row)*76];
    d32[0]  = 0;
    d32[33] = 0;
    u32* di = d32 + 1;
    int yg = y0 - 2 + row;
    if (yg >= 0 && yg < 64){
      const uint4* srcp = (const uint4*)&hb[ (((size_t)gl*32 + b)*32 + c2)*4096 + (size_t)yg*64 ];
      #pragma unroll
      for (int q=0;q<8;q++){
        uint4 v = srcp[q];
        di[q*4+0]=v.x; di[q*4+1]=v.y; di[q*4+2]=v.z; di[q*4+3]=v.w;
      }
    } else {
      #pragma unroll
      for (int q=0;q<32;q++) di[q] = 0;
    }
  }
  for (int idx=t; idx<800; idx+=256) wcL[idx] = wc[idx];
  __syncthreads();

  const int xt = t&7, yq = (t>>3)&7, cqt = t>>6;
  const int x0 = xt*8;
  float acc[8];
  #pragma unroll
  for (int p=0;p<8;p++) acc[p]=0.f;
  for (int c2 = cqt*8; c2 < cqt*8+8; c2++){
    #pragma unroll
    for (int dy=0;dy<5;dy++){
      const uint2* hp = (const uint2*)&hbT[(c2*12 + yq+dy)*76 + x0];
      uint2 v0 = hp[0], v1 = hp[1], v2 = hp[2];
      float h[12];
      h[0]=lo2f(v0.x); h[1]=hi2f(v0.x); h[2]=lo2f(v0.y); h[3]=hi2f(v0.y);
      h[4]=lo2f(v1.x); h[5]=hi2f(v1.x); h[6]=lo2f(v1.y); h[7]=hi2f(v1.y);
      h[8]=lo2f(v2.x); h[9]=hi2f(v2.x); h[10]=lo2f(v2.y); h[11]=hi2f(v2.y);
      #pragma unroll
      for (int dx=0;dx<5;dx++){
        float wv = wcL[c2*25 + dy*5 + dx];
        #pragma unroll
        for (int p=0;p<8;p++) acc[p] = fmaf(h[p+dx], wv, acc[p]);
      }
    }
  }
  __syncthreads();
  int slot = yq*8 + xt;
  if (cqt >= 2){
    #pragma unroll
    for (int p=0;p<8;p++) redc[((cqt-2)*64 + slot)*8 + p] = acc[p];
  }
  __syncthreads();
  if (cqt < 2){
    #pragma unroll
    for (int p=0;p<8;p++) acc[p] += redc[(cqt*64 + slot)*8 + p];
  }
  __syncthreads();
  if (cqt == 1){
    #pragma unroll
    for (int p=0;p<8;p++) redc[slot*8 + p] = acc[p];
  }
  __syncthreads();
  if (cqt == 0){
    float bcv = bc[0];
    size_t base = (((size_t)g*32 + b)*64 + (y0+yq))*64 + x0;
    #pragma unroll
    for (int p=0;p<8;p++) rec[base+p] = acc[p] + redc[slot*8 + p] + bcv;
  }
}

// ---------------- final: out[b,y,x,o] = s3[b,o,y,x] + rec[o,b,y,x] (f32) ----------------
__global__ __launch_bounds__(256) void k_final(const float* __restrict__ s3,
        const float* __restrict__ rec, float* __restrict__ out){
  __shared__ float tile[31][65];
  const int t = threadIdx.x;
  const int y = blockIdx.x & 63;
  const int b = blockIdx.x >> 6;
  for (int idx=t; idx<1984; idx+=256){
    int o = idx>>6, x = idx&63;
    tile[o][x] = s3[ (((size_t)b*31+o)*64 + y)*64 + x ]
               + rec[ (((size_t)o*32+b)*64 + y)*64 + x ];
  }
  __syncthreads();
  size_t base = ((size_t)b*4096 + (size_t)y*64)*31;
  for (int idx=t; idx<1984; idx+=256){
    int x = idx/31, o = idx-31*x;
    out[base+idx] = tile[o][x];
  }
}

extern "C" void kernel_launch(void* const* d_in, const int* in_sizes, int n_in,
                              void* d_out, int out_size, void* d_ws, size_t ws_size,
                              hipStream_t stream){
  const float* x    = (const float*)d_in[0];
  const float* W1   = (const float*)d_in[1];
  const float* b1   = (const float*)d_in[2];
  const float* W2   = (const float*)d_in[3];
  const float* b2   = (const float*)d_in[4];
  const float* W3   = (const float*)d_in[5];
  const float* b3   = (const float*)d_in[6];
  const float* We1a = (const float*)d_in[7];
  const float* be1a = (const float*)d_in[8];
  const float* We1b = (const float*)d_in[9];
  const float* be1b = (const float*)d_in[10];
  const float* We1c = (const float*)d_in[11];
  const float* be1c = (const float*)d_in[12];
  const float* We2a = (const float*)d_in[13];
  const float* be2a = (const float*)d_in[14];
  const float* We2b = (const float*)d_in[15];
  const float* be2b = (const float*)d_in[16];
  const float* We2c = (const float*)d_in[17];
  const float* be2c = (const float*)d_in[18];
  float* out = (float*)d_out;

  // ws layout (time-multiplexed):
  //  spatial phase: s3 @0 (15.5M) | Wp @16M (<=24.4M) | xT @42M (0.5M)
  //  spec phase:    s3 @0         | rec @16M (15.5M)  | hb slabs @33030144 (8.39M each)
  char* ws = (char*)d_ws;
  float* s3  = (float*)(ws);
  u16*   Wp  = (u16*)(ws + 16777216);
  u16*   xT  = (u16*)(ws + 44040192);
  float* rec = (float*)(ws + 16777216);
  u16*   hb  = (u16*)(ws + 33030144);

  // d_out scratch (dead until k_final):
  //  spatial phase: bufA @0 (natural, 8.13M), bufB @8126464 (transposed, 8.13M)
  //  spec phase:    waP @0 (1.43M), wbP @1440000
  u16* bufA = (u16*)((char*)d_out);
  u16* bufB = (u16*)((char*)d_out + 8126464);
  u16* waP = (u16*)((char*)d_out);
  u16* wbP = (u16*)((char*)d_out + 1440000);

  dim3 bs(256);
  dim3 gsp(512), gtr(32,31);
  k_prep_x<<<dim3(32),bs,0,stream>>>(x, xT);
  k_prep_w<<<dim3(64,1),bs,0,stream>>>(W1, Wp, 1);
  k_spatial2<<<gsp,bs,0,stream>>>(xT,  Wp, b1, nullptr, bufA, 1, 1);
  k_tr<<<gtr,bs,0,stream>>>(bufA, bufB);
  k_prep_w<<<dim3(64,31),bs,0,stream>>>(W2, Wp, 31);
  k_spatial2<<<gsp,bs,0,stream>>>(bufB, Wp, b2, nullptr, bufA, 31, 1);
  k_tr<<<gtr,bs,0,stream>>>(bufA, bufB);
  k_prep_w<<<dim3(64,31),bs,0,stream>>>(W3, Wp, 31);
  k_spatial2<<<gsp,bs,0,stream>>>(bufB, Wp, b3, s3, nullptr, 31, 0);

  k_prep<<<dim3(74),bs,0,stream>>>(We1a, We2a, We1b, We2b, waP, wbP);

  // gl batch: cap at 8 so hb slab (67 MB) stays L3-resident
  int batch = 8;
  if (ws_size > 33030144ull){
    size_t m = (ws_size - 33030144ull) / 8388608ull;
    if (m < 1) m = 1;
    if (m > 8) m = 8;
    batch = (int)m;
  }
  for (int g0=0; g0<31; g0+=batch){
    int c = 31 - g0; if (c > batch) c = batch;
    k_spec_ab<<<dim3(16,32,c),bs,0,stream>>>(s3, waP, wbP, be1a, be1b, be2a, be2b, hb, g0);
    k_spec_c <<<dim3(8,32,c),bs,0,stream>>>(hb, We1c,be1c,We2c,be2c, rec, g0);
  }
  k_final<<<dim3(2048),bs,0,stream>>>(s3, rec, out);
}

// Round 9
// 957.484 us; speedup vs baseline: 1.1827x; 1.0303x over previous
//
#include <hip/hip_runtime.h>
#include <hip/hip_bf16.h>
#include <stdint.h>

typedef unsigned short u16;
typedef unsigned int   u32;
typedef __attribute__((ext_vector_type(8))) short bf16x8;
typedef __attribute__((ext_vector_type(4))) float f32x4;

__device__ __forceinline__ float us2f(u16 u){ return __uint_as_float(((u32)u)<<16); }
__device__ __forceinline__ float lo2f(u32 w){ return __uint_as_float(w<<16); }
__device__ __forceinline__ float hi2f(u32 w){ return __uint_as_float(w & 0xffff0000u); }
__device__ __forceinline__ u16 f2us(float f){
  u32 u = __float_as_uint(f);
  u32 r = (u + 0x7FFFu + ((u>>16)&1u)) >> 16;   // RNE
  return (u16)r;
}
__device__ __forceinline__ u32 pk2(float a, float b){ return (u32)f2us(a) | ((u32)f2us(b)<<16); }

// ---------------- prep: x (b,r,w) f32 -> xT[b][w][r] bf16 ----------------
__global__ __launch_bounds__(256) void k_prep_x(const float* __restrict__ x, u16* __restrict__ xT){
  __shared__ float tile[64][65];
  const int b = blockIdx.x, t = threadIdx.x;
  #pragma unroll
  for (int q=0;q<4;q++){
    int idx = q*256 + t, r = idx>>4, w4 = (idx&15)*4;
    float4 v = *(const float4*)&x[((size_t)b*64 + r)*64 + w4];
    tile[r][w4]=v.x; tile[r][w4+1]=v.y; tile[r][w4+2]=v.z; tile[r][w4+3]=v.w;
  }
  __syncthreads();
  #pragma unroll
  for (int q=0;q<2;q++){
    int idx = q*256 + t, w = idx>>3, rc = idx&7;
    uint4 o;
    o.x = pk2(tile[rc*8+0][w], tile[rc*8+1][w]);
    o.y = pk2(tile[rc*8+2][w], tile[rc*8+3][w]);
    o.z = pk2(tile[rc*8+4][w], tile[rc*8+5][w]);
    o.w = pk2(tile[rc*8+6][w], tile[rc*8+7][w]);
    *(uint4*)&xT[((size_t)b*64 + w)*64 + rc*8] = o;
  }
}

// ---------------- prep: W (64h,31o,CI,64r,3dw) f32 -> Wp[h][i][dw][o32][r64] bf16 ----------------
__global__ __launch_bounds__(256) void k_prep_w(const float* __restrict__ W,
        u16* __restrict__ Wp, int CI){
  __shared__ float rowW[5952];   // [o 31][j 192]
  const int h = blockIdx.x, i = blockIdx.y, t = threadIdx.x;
  for (int idx=t; idx<1488; idx+=256){
    int o = idx/48, j4 = (idx - o*48)*4;
    float4 v = *(const float4*)&W[ (((size_t)h*31 + o)*CI + i)*192 + j4 ];
    *(float4*)&rowW[o*192 + j4] = v;
  }
  __syncthreads();
  for (int idx=t; idx<768; idx+=256){
    int dw = idx>>8, rem = idx&255, o = rem>>3, rc = rem&7;
    uint4 ov = {0,0,0,0};
    if (o < 31){
      const float* s = &rowW[o*192 + dw];
      ov.x = pk2(s[(rc*8+0)*3], s[(rc*8+1)*3]);
      ov.y = pk2(s[(rc*8+2)*3], s[(rc*8+3)*3]);
      ov.z = pk2(s[(rc*8+4)*3], s[(rc*8+5)*3]);
      ov.w = pk2(s[(rc*8+6)*3], s[(rc*8+7)*3]);
    }
    *(uint4*)&Wp[ ((((size_t)h*CI + i)*3 + dw)*32 + o)*64 + rc*8 ] = ov;
  }
}

// ---------------- bf16 transpose: in[b][o][h][w] -> out[b][o][w][h] ----------------
__global__ __launch_bounds__(256) void k_tr(const u16* __restrict__ in, u16* __restrict__ outp){
  __shared__ u16 tile[64*72];
  const int b = blockIdx.x, o = blockIdx.y, t = threadIdx.x;
  const uint4* src = (const uint4*)(in + ((size_t)b*31 + o)*4096);
  #pragma unroll
  for (int q=0;q<2;q++){
    int idx = q*256 + t, hh = idx>>3, u = idx&7;
    *(uint4*)&tile[hh*72 + ((u ^ ((hh>>3)&7))*8)] = src[idx];
  }
  __syncthreads();
  u16* dst = outp + ((size_t)b*31 + o)*4096;
  #pragma unroll
  for (int q=0;q<2;q++){
    int idx = q*256 + t, w = idx>>3, hc = (idx&7)*8;
    u32 ow[4];
    #pragma unroll
    for (int j=0;j<4;j++){
      int h0 = hc + j*2, h1 = h0 + 1;
      u16 a = tile[h0*72 + (((w>>3) ^ ((h0>>3)&7))*8) + (w&7)];
      u16 bb= tile[h1*72 + (((w>>3) ^ ((h1>>3)&7))*8) + (w&7)];
      ow[j] = (u32)a | ((u32)bb<<16);
    }
    uint4 ov = {ow[0], ow[1], ow[2], ow[3]};
    *(uint4*)&dst[(size_t)w*64 + hc] = ov;
  }
}

// ---------------- spatial layer via MFMA, o-split waves ----------------
// inT_g: [b][i][w][r] bf16 ; Wp: [h][i][dw][o32][r64] bf16 ; bias (64,31) f32
// mode 0: outF[b][o][h][w] f32 ; mode 1: outT[b][o][h][w] bf16 (natural; k_tr transposes)
// 512 threads = 8 waves: wave = (h = hg*4 + (wv&3), o-half = wv>>2). The o-split
// conserves ALL traffic (each wave loads only its weight half, input slab shared)
// while doubling wave count to 16/CU. Same proven pipeline: reg-prefetch input
// ch i+1 + weight frags i+1 (dbuf) + lgkm-only barrier.
// hg tied to XCD (8 h per XCD -> 3 MB Wp slice L2-resident).
__global__ __launch_bounds__(512) void k_spatial2(const u16* __restrict__ inT_g,
        const u16* __restrict__ Wp, const float* __restrict__ bias,
        float* __restrict__ outF, u16* __restrict__ outT, int CI, int mode){
  __shared__ __align__(16) u16 inT[2][66*72];   // [wext 0..65][r pad72], rows 0/65 zero
  const int t    = threadIdx.x;
  const int wv   = t>>6;            // 0..7
  const int lane = t&63;
  const int l15  = lane&15;
  const int quad = lane>>4;
  // 512 blocks = 8 xcd * (2 hg * 32 b): hg tied to xcd -> per-XCD Wp slice 3 MB
  const int wg  = blockIdx.x;
  const int xcd = wg & 7;
  const int li  = wg >> 3;
  const int hg  = xcd*2 + (li>>5);
  const int b   = li & 31;
  const int h   = hg*4 + (wv&3);
  const int nho = wv>>2;            // o-half: 0 -> o 0..15, 1 -> o 16..31

  if (t < 72){
    inT[0][t] = 0; inT[0][65*72 + t] = 0;
    inT[1][t] = 0; inT[1][65*72 + t] = 0;
  }

  f32x4 acc[4];
  #pragma unroll
  for (int ms=0;ms<4;ms++) acc[ms] = (f32x4){0.f,0.f,0.f,0.f};

  const uint4* srcb = (const uint4*)(inT_g + (size_t)b*CI*4096);
  const u16*   wr   = Wp + (size_t)h*CI*3*32*64;

  // prologue: prefetch channel 0 input (1 uint4/thread) + channel-0 weight frags (this o-half)
  uint4 pf = srcb[t];
  bf16x8 bA[2][3], bB[2][3];
  #pragma unroll
  for (int dw=0;dw<3;dw++)
    #pragma unroll
    for (int kh=0;kh<2;kh++)
      bA[kh][dw] = *(const bf16x8*)&wr[(dw*32 + nho*16 + l15)*64 + kh*32 + quad*8];

  auto body = [&](bf16x8 (&bcur)[2][3], bf16x8 (&bnext)[2][3], int i){
    u16* L = inT[i&1];
    // write prefetched channel i into LDS (rows w=0..63 -> wext=1..64)
    {
      int row = t>>3, ch = t&7;
      *(uint4*)&L[(row+1)*72 + ch*8] = pf;
    }
    // issue prefetches for channel i+1 (clamped; consumed next iteration)
    int inext = (i+1 < CI) ? (i+1) : (CI-1);
    pf = (srcb + (size_t)inext*512)[t];
    const u16* wbase = wr + (size_t)inext*6144;   // 3*32*64
    #pragma unroll
    for (int dw=0;dw<3;dw++)
      #pragma unroll
      for (int kh=0;kh<2;kh++)
        bnext[kh][dw] = *(const bf16x8*)&wbase[(dw*32 + nho*16 + l15)*64 + kh*32 + quad*8];
    // lgkm-only drain: ds_writes visible; vmcnt prefetches stay in flight
    asm volatile("s_waitcnt lgkmcnt(0)" ::: "memory");
    __builtin_amdgcn_s_barrier();
    __builtin_amdgcn_sched_barrier(0);
    #pragma unroll
    for (int kh=0; kh<2; kh++){
      #pragma unroll
      for (int dw=0; dw<3; dw++){
        bf16x8 afr[4];
        #pragma unroll
        for (int ms=0;ms<4;ms++)
          afr[ms] = *(const bf16x8*)&L[(ms*16 + l15 + dw)*72 + kh*32 + quad*8];
        #pragma unroll
        for (int ms=0;ms<4;ms++)
          acc[ms] = __builtin_amdgcn_mfma_f32_16x16x32_bf16(afr[ms], bcur[kh][dw], acc[ms], 0,0,0);
      }
    }
  };

  int i = 0;
  while (true){
    body(bA, bB, i); if (++i >= CI) break;
    body(bB, bA, i); if (++i >= CI) break;
  }

  // epilogue: D col=lane&15 -> o (within half), row=quad*4+reg -> w ; NATURAL [b][o][h][w]
  {
    int o = nho*16 + l15;
    if (o < 31){
      float bv = bias[h*31 + o];
      if (mode == 0){
        #pragma unroll
        for (int ms=0;ms<4;ms++){
          size_t base = (((size_t)b*31 + o)*64 + h)*64 + ms*16 + quad*4;
          #pragma unroll
          for (int reg=0;reg<4;reg++)
            outF[base + reg] = fmaxf(acc[ms][reg] + bv, 0.f);
        }
      } else {
        #pragma unroll
        for (int ms=0;ms<4;ms++){
          uint2 pw;
          pw.x = pk2(fmaxf(acc[ms][0] + bv, 0.f), fmaxf(acc[ms][1] + bv, 0.f));
          pw.y = pk2(fmaxf(acc[ms][2] + bv, 0.f), fmaxf(acc[ms][3] + bv, 0.f));
          *(uint2*)&outT[ (((size_t)b*31 + o)*64 + h)*64 + ms*16 + quad*4 ] = pw;
        }
      }
    }
  }
}

// ---------------- prep: spec weights -> GEMM-ready bf16 ----------------
__global__ __launch_bounds__(256) void k_prep(
    const float* __restrict__ We1a, const float* __restrict__ We2a,
    const float* __restrict__ We1b, const float* __restrict__ We2b,
    u16* __restrict__ waP, u16* __restrict__ wbP){
  int t = blockIdx.x*256 + threadIdx.x;
  if (t < 17856){
    int g = t/576, rem = t - g*576, dx = rem>>6, c = rem&63;
    int C; const float* wa;
    if (g==0)      { C=2; wa = We1a; }
    else if (g==30){ C=2; wa = We1a + 64*2*81; }
    else           { C=3; wa = We2a + (size_t)(g-1)*64*3*81; }
    const float* wrow = wa + (size_t)c*C*81;
    u16* dst = waP + ((size_t)(g*9 + dx)*64 + c)*40;
    int Kr = C*9;
    for (int k=0;k<40;k++){
      u16 v = 0;
      if (k < Kr) v = f2us(wrow[k*9 + dx]);
      dst[k] = v;
    }
  } else if (t < 17856 + 992){
    int u = t - 17856; int g = u>>5, c2 = u&31;
    const float* wb;
    if (g==0)      wb = We1b;
    else if (g==30) wb = We1b + 32*64;
    else            wb = We2b + (size_t)(g-1)*32*64;
    u16* dst = wbP + ((size_t)g*32 + c2)*72;
    for (int k=0;k<64;k++) dst[k] = f2us(wb[c2*64 + k]);
    for (int k=64;k<72;k++) dst[k] = 0;
  }
}

// ---------------- spectral a+b via MFMA (gl-batched) ----------------
__global__ __launch_bounds__(256) void k_spec_ab(
    const float* __restrict__ s3,
    const u16* __restrict__ waP, const u16* __restrict__ wbP,
    const float* __restrict__ be1a, const float* __restrict__ be1b,
    const float* __restrict__ be2a, const float* __restrict__ be2b,
    u16* __restrict__ hb, int g0){
  __shared__ __align__(16) unsigned char smem[36864];
  u16* colT  = (u16*)smem;            // [4][72][40]   phase A (im2col input), 23040 B
  u16* stage = (u16*)(smem + 23040);  // [3][12][64]   phase A s3 row stage, 4608 B
  u16* haT   = (u16*)smem;            // [256][72]     phase B (overlay after barrier)
  u16* hbL   = (u16*)smem;            // [32][296]     phase C (overlay after barrier)

  const int t = threadIdx.x;
  const int yo = blockIdx.x, b = blockIdx.y;
  const int gl = blockIdx.z;
  const int g  = g0 + gl;
  const int y0 = yo*4;
  const int wv = t>>6, lane = t&63, l15 = lane&15, quad = lane>>4;

  int C, cb; const float *ba, *bb;
  if (g==0)      { C=2; cb=0;  ba=be1a;           bb=be1b;        }
  else if (g==30){ C=2; cb=29; ba=be1a+64;        bb=be1b+32;     }
  else           { C=3; cb=g-1; ba=be2a+(size_t)(g-1)*64; bb=be2b+(size_t)(g-1)*32; }

  // A1: x-pad zero (colT cols 0..3, 68..71) + bf16 row stage (12 yext rows, once)
  if (t < 160){
    int yl = t/40, rem = t - yl*40, xi = rem/5, q = rem - xi*5;
    int xc = (xi < 4) ? xi : xi + 64;
    *(uint4*)&colT[(yl*72 + xc)*40 + q*8] = (uint4){0,0,0,0};
  }
  for (int idx=t; idx<576; idx+=256){
    int i = idx/192, rem = idx-192*i, yext = rem>>4, x4 = rem&15;
    int yrow = y0 + yext - 4;
    uint2 sv = {0,0};
    if (i < C && yrow >= 0 && yrow < 64){
      float4 v = *(const float4*)&s3[ (((size_t)b*31 + cb + i)*64 + yrow)*64 + x4*4 ];
      sv.x = pk2(v.x, v.y);
      sv.y = pk2(v.z, v.w);
    }
    *(uint2*)&stage[(i*12 + yext)*64 + x4*4] = sv;
  }
  __syncthreads();

  // A2: dense gather -> colT[(yl*72 + x + 4)*40 + k], exactly 1 px per thread
  {
    const int yl = t>>6, x = t&63;
    const int C9 = C*9;
    u32 wbuf[20];
    #pragma unroll
    for (int kk=0;kk<20;kk++){
      int k0 = kk*2, k1 = kk*2+1;
      int i0 = k0/9, dy0 = k0 - i0*9;
      int i1 = k1/9, dy1 = k1 - i1*9;
      int ii0 = (k0 < C9) ? i0 : 0;
      int ii1 = (k1 < C9) ? i1 : 0;
      u32 v0 = (k0 < C9) ? (u32)stage[(ii0*12 + (yl+dy0))*64 + x] : 0u;
      u32 v1 = (k1 < C9) ? (u32)stage[(ii1*12 + (yl+dy1))*64 + x] : 0u;
      wbuf[kk] = v0 | (v1<<16);
    }
    u16* dst = &colT[(yl*72 + x + 4)*40];
    #pragma unroll
    for (int q=0;q<5;q++){
      uint4 ov = { wbuf[q*4], wbuf[q*4+1], wbuf[q*4+2], wbuf[q*4+3] };
      *(uint4*)&dst[q*8] = ov;
    }
  }
  __syncthreads();

  f32x4 acc[4][4];
  #pragma unroll
  for (int yl=0;yl<4;yl++)
    #pragma unroll
    for (int nf=0;nf<4;nf++) acc[yl][nf] = (f32x4){0.f,0.f,0.f,0.f};

  const u16* waPg = waP + (size_t)g*9*64*40;
  #pragma unroll
  for (int dx=0; dx<9; dx++){
    bf16x8 af[4];
    #pragma unroll
    for (int yl=0;yl<4;yl++)
      af[yl] = *(const bf16x8*)&colT[(yl*72 + wv*16 + l15 + dx)*40 + quad*8];
    #pragma unroll
    for (int nf=0;nf<4;nf++){
      bf16x8 bfr = *(const bf16x8*)&waPg[(dx*64 + nf*16 + l15)*40 + quad*8];
      #pragma unroll
      for (int yl=0;yl<4;yl++)
        acc[yl][nf] = __builtin_amdgcn_mfma_f32_16x16x32_bf16(af[yl], bfr, acc[yl][nf], 0,0,0);
    }
  }
  __syncthreads();   // colT/stage dead -> haT may overlay

  #pragma unroll
  for (int nf=0;nf<4;nf++){
    float bav = ba[nf*16 + l15];
    #pragma unroll
    for (int yl=0;yl<4;yl++){
      int px = yl*64 + wv*16 + quad*4;
      #pragma unroll
      for (int reg=0;reg<4;reg++)
        haT[(px+reg)*72 + nf*16 + l15] = f2us(fmaxf(acc[yl][nf][reg] + bav, 0.f));
    }
  }
  __syncthreads();

  // preload all phase-B A fragments, then retire haT so hbL can overlay
  bf16x8 a2[2][4];
  #pragma unroll
  for (int kh=0; kh<2; kh++)
    #pragma unroll
    for (int j=0;j<4;j++)
      a2[kh][j] = *(const bf16x8*)&haT[((wv*4+j)*16 + l15)*72 + kh*32 + quad*8];
  __syncthreads();   // haT dead -> hbL may overlay

  const u16* wb_g = wbP + (size_t)g*32*72;
  f32x4 acc2[4][2];
  #pragma unroll
  for (int j=0;j<4;j++){ acc2[j][0] = (f32x4){0.f,0.f,0.f,0.f}; acc2[j][1] = (f32x4){0.f,0.f,0.f,0.f}; }
  #pragma unroll
  for (int kh=0; kh<2; kh++){
    #pragma unroll
    for (int nf=0;nf<2;nf++){
      bf16x8 b2 = *(const bf16x8*)&wb_g[(nf*16 + l15)*72 + kh*32 + quad*8];
      #pragma unroll
      for (int j=0;j<4;j++)
        acc2[j][nf] = __builtin_amdgcn_mfma_f32_16x16x32_bf16(a2[kh][j], b2, acc2[j][nf], 0,0,0);
    }
  }
  // packed uint2 stores, row stride 296 u16 (bank stride 20 -> ~2-way)
  #pragma unroll
  for (int nf=0;nf<2;nf++){
    float bbv = bb[nf*16 + l15];
    #pragma unroll
    for (int j=0;j<4;j++){
      int px = (wv*4+j)*16 + quad*4;
      uint2 pw;
      pw.x = pk2(fmaxf(acc2[j][nf][0] + bbv, 0.f), fmaxf(acc2[j][nf][1] + bbv, 0.f));
      pw.y = pk2(fmaxf(acc2[j][nf][2] + bbv, 0.f), fmaxf(acc2[j][nf][3] + bbv, 0.f));
      *(uint2*)&hbL[(nf*16+l15)*296 + px] = pw;
    }
  }
  __syncthreads();

  {
    int c2 = t>>3, xq = t&7;
    size_t base = (((size_t)gl*32 + b)*32 + c2)*4096 + (size_t)yo*256 + xq*32;
    #pragma unroll
    for (int q=0;q<4;q++)
      *(uint4*)&hb[base + q*8] = *(const uint4*)&hbL[c2*296 + xq*32 + q*8];
  }
}

// ---------------- spectral: 5x5 conv 32->1, writes rec f32 [g][b][y][x] ----------------
__global__ __launch_bounds__(256) void k_spec_c(
    const u16* __restrict__ hb, const float* __restrict__ We1c, const float* __restrict__ be1c,
    const float* __restrict__ We2c, const float* __restrict__ be2c,
    float* __restrict__ rec, int g0){
  __shared__ __align__(16) unsigned char smemC[58368 + 3200];
  u16*   hbT  = (u16*)smemC;                 // [32][12][76] bf16
  float* wcL  = (float*)(smemC + 58368);     // [32][25]
  float* redc = (float*)smemC;               // overlay after compute
  const int t  = threadIdx.x;
  const int y0 = blockIdx.x*8;
  const int b  = blockIdx.y;
  const int gl = blockIdx.z;
  const int g  = g0 + gl;
  const float *wc, *bc;
  if (g==0)      { wc = We1c;             bc = be1c;       }
  else if (g==30){ wc = We1c + 800;       bc = be1c + 1;   }
  else           { wc = We2c + (g-1)*800; bc = be2c + (g-1); }

  for (int idx=t; idx<384; idx+=256){
    int c2 = idx/12, row = idx - c2*12;
    u32* d32 = (u32*)&hbT[(size_t)(c2*12 + row)*76];
    d32[0]  = 0;
    d32[33] = 0;
    u32* di = d32 + 1;
    int yg = y0 - 2 + row;
    if (yg >= 0 && yg < 64){
      const uint4* srcp = (const uint4*)&hb[ (((size_t)gl*32 + b)*32 + c2)*4096 + (size_t)yg*64 ];
      #pragma unroll
      for (int q=0;q<8;q++){
        uint4 v = srcp[q];
        di[q*4+0]=v.x; di[q*4+1]=v.y; di[q*4+2]=v.z; di[q*4+3]=v.w;
      }
    } else {
      #pragma unroll
      for (int q=0;q<32;q++) di[q] = 0;
    }
  }
  for (int idx=t; idx<800; idx+=256) wcL[idx] = wc[idx];
  __syncthreads();

  const int xt = t&7, yq = (t>>3)&7, cqt = t>>6;
  const int x0 = xt*8;
  float acc[8];
  #pragma unroll
  for (int p=0;p<8;p++) acc[p]=0.f;
  for (int c2 = cqt*8; c2 < cqt*8+8; c2++){
    #pragma unroll
    for (int dy=0;dy<5;dy++){
      const uint2* hp = (const uint2*)&hbT[(c2*12 + yq+dy)*76 + x0];
      uint2 v0 = hp[0], v1 = hp[1], v2 = hp[2];
      float h[12];
      h[0]=lo2f(v0.x); h[1]=hi2f(v0.x); h[2]=lo2f(v0.y); h[3]=hi2f(v0.y);
      h[4]=lo2f(v1.x); h[5]=hi2f(v1.x); h[6]=lo2f(v1.y); h[7]=hi2f(v1.y);
      h[8]=lo2f(v2.x); h[9]=hi2f(v2.x); h[10]=lo2f(v2.y); h[11]=hi2f(v2.y);
      #pragma unroll
      for (int dx=0;dx<5;dx++){
        float wv = wcL[c2*25 + dy*5 + dx];
        #pragma unroll
        for (int p=0;p<8;p++) acc[p] = fmaf(h[p+dx], wv, acc[p]);
      }
    }
  }
  __syncthreads();
  int slot = yq*8 + xt;
  if (cqt >= 2){
    #pragma unroll
    for (int p=0;p<8;p++) redc[((cqt-2)*64 + slot)*8 + p] = acc[p];
  }
  __syncthreads();
  if (cqt < 2){
    #pragma unroll
    for (int p=0;p<8;p++) acc[p] += redc[(cqt*64 + slot)*8 + p];
  }
  __syncthreads();
  if (cqt == 1){
    #pragma unroll
    for (int p=0;p<8;p++) redc[slot*8 + p] = acc[p];
  }
  __syncthreads();
  if (cqt == 0){
    float bcv = bc[0];
    size_t base = (((size_t)g*32 + b)*64 + (y0+yq))*64 + x0;
    #pragma unroll
    for (int p=0;p<8;p++) rec[base+p] = acc[p] + redc[slot*8 + p] + bcv;
  }
}

// ---------------- final: out[b,y,x,o] = s3[b,o,y,x] + rec[o,b,y,x] (f32) ----------------
__global__ __launch_bounds__(256) void k_final(const float* __restrict__ s3,
        const float* __restrict__ rec, float* __restrict__ out){
  __shared__ float tile[31][65];
  const int t = threadIdx.x;
  const int y = blockIdx.x & 63;
  const int b = blockIdx.x >> 6;
  for (int idx=t; idx<1984; idx+=256){
    int o = idx>>6, x = idx&63;
    tile[o][x] = s3[ (((size_t)b*31+o)*64 + y)*64 + x ]
               + rec[ (((size_t)o*32+b)*64 + y)*64 + x ];
  }
  __syncthreads();
  size_t base = ((size_t)b*4096 + (size_t)y*64)*31;
  for (int idx=t; idx<1984; idx+=256){
    int x = idx/31, o = idx-31*x;
    out[base+idx] = tile[o][x];
  }
}

extern "C" void kernel_launch(void* const* d_in, const int* in_sizes, int n_in,
                              void* d_out, int out_size, void* d_ws, size_t ws_size,
                              hipStream_t stream){
  const float* x    = (const float*)d_in[0];
  const float* W1   = (const float*)d_in[1];
  const float* b1   = (const float*)d_in[2];
  const float* W2   = (const float*)d_in[3];
  const float* b2   = (const float*)d_in[4];
  const float* W3   = (const float*)d_in[5];
  const float* b3   = (const float*)d_in[6];
  const float* We1a = (const float*)d_in[7];
  const float* be1a = (const float*)d_in[8];
  const float* We1b = (const float*)d_in[9];
  const float* be1b = (const float*)d_in[10];
  const float* We1c = (const float*)d_in[11];
  const float* be1c = (const float*)d_in[12];
  const float* We2a = (const float*)d_in[13];
  const float* be2a = (const float*)d_in[14];
  const float* We2b = (const float*)d_in[15];
  const float* be2b = (const float*)d_in[16];
  const float* We2c = (const float*)d_in[17];
  const float* be2c = (const float*)d_in[18];
  float* out = (float*)d_out;

  // ws layout (time-multiplexed):
  //  spatial phase: s3 @0 (15.5M) | Wp @16M (<=24.4M) | xT @42M (0.5M)
  //  spec phase:    s3 @0         | rec @16M (15.5M)  | hb slabs @33030144 (8.39M each)
  char* ws = (char*)d_ws;
  float* s3  = (float*)(ws);
  u16*   Wp  = (u16*)(ws + 16777216);
  u16*   xT  = (u16*)(ws + 44040192);
  float* rec = (float*)(ws + 16777216);
  u16*   hb  = (u16*)(ws + 33030144);

  // d_out scratch (dead until k_final):
  //  spatial phase: bufA @0 (natural, 8.13M), bufB @8126464 (transposed, 8.13M)
  //  spec phase:    waP @0 (1.43M), wbP @1440000
  u16* bufA = (u16*)((char*)d_out);
  u16* bufB = (u16*)((char*)d_out + 8126464);
  u16* waP = (u16*)((char*)d_out);
  u16* wbP = (u16*)((char*)d_out + 1440000);

  dim3 bs(256);
  dim3 gsp(512), bsp(512), gtr(32,31);
  k_prep_x<<<dim3(32),bs,0,stream>>>(x, xT);
  k_prep_w<<<dim3(64,1),bs,0,stream>>>(W1, Wp, 1);
  k_spatial2<<<gsp,bsp,0,stream>>>(xT,  Wp, b1, nullptr, bufA, 1, 1);
  k_tr<<<gtr,bs,0,stream>>>(bufA, bufB);
  k_prep_w<<<dim3(64,31),bs,0,stream>>>(W2, Wp, 31);
  k_spatial2<<<gsp,bsp,0,stream>>>(bufB, Wp, b2, nullptr, bufA, 31, 1);
  k_tr<<<gtr,bs,0,stream>>>(bufA, bufB);
  k_prep_w<<<dim3(64,31),bs,0,stream>>>(W3, Wp, 31);
  k_spatial2<<<gsp,bsp,0,stream>>>(bufB, Wp, b3, s3, nullptr, 31, 0);

  k_prep<<<dim3(74),bs,0,stream>>>(We1a, We2a, We1b, We2b, waP, wbP);

  // gl batch: cap at 8 so hb slab (67 MB) stays L3-resident
  int batch = 8;
  if (ws_size > 33030144ull){
    size_t m = (ws_size - 33030144ull) / 8388608ull;
    if (m < 1) m = 1;
    if (m > 8) m = 8;
    batch = (int)m;
  }
  for (int g0=0; g0<31; g0+=batch){
    int c = 31 - g0; if (c > batch) c = batch;
    k_spec_ab<<<dim3(16,32,c),bs,0,stream>>>(s3, waP, wbP, be1a, be1b, be2a, be2b, hb, g0);
    k_spec_c <<<dim3(8,32,c),bs,0,stream>>>(hb, We1c,be1c,We2c,be2c, rec, g0);
  }
  k_final<<<dim3(2048),bs,0,stream>>>(s3, rec, out);
}